// Round 12
// baseline (321.009 us; speedup 1.0000x reference)
//
#include <hip/hip_runtime.h>

typedef __attribute__((ext_vector_type(8))) short short8;
typedef __attribute__((ext_vector_type(4))) float f32x4;
typedef __attribute__((ext_vector_type(4))) int int4v;
typedef __attribute__((ext_vector_type(4))) unsigned int u32x4;

#define THRE 4.0f

#define GLOAD_LDS16(g, l) \
    __builtin_amdgcn_global_load_lds((const __attribute__((address_space(1))) void*)(g), \
                                     (__attribute__((address_space(3))) void*)(l), 16, 0, 0)

__device__ __forceinline__ float spikef(float x) {
    return floorf(fminf(fmaxf(x, 0.0f), THRE) + 0.5f);
}
__device__ __forceinline__ unsigned short f2bf(float f) {
    return (unsigned short)(__builtin_bit_cast(unsigned int, f) >> 16);
}
__device__ __forceinline__ unsigned short f2bf_rn(float f) {
    unsigned u = __builtin_bit_cast(unsigned int, f);
    unsigned r = ((u >> 16) & 1u) + 0x7FFFu;
    return (unsigned short)((u + r) >> 16);
}
__device__ __forceinline__ float bf2f(unsigned short s) {
    return __builtin_bit_cast(float, (unsigned int)s << 16);
}
__device__ __forceinline__ int4v mfma_i8(u32x4 a, u32x4 b, int4v c) {
    return __builtin_amdgcn_mfma_i32_16x16x64_i8(__builtin_bit_cast(int4v, a),
                                                 __builtin_bit_cast(int4v, b), c, 0, 0, 0);
}

#define NB 512

// device-scope grid barrier: cnt/gen zeroed by hipMemsetAsync before launch.
__device__ __forceinline__ void grid_barrier(int* cnt, int* gen) {
    __syncthreads();
    if (threadIdx.x == 0) {
        __threadfence();                                   // release
        int g = atomicAdd(gen, 0);
        if (atomicAdd(cnt, 1) == NB - 1) {
            atomicExch(cnt, 0);
            __threadfence();
            atomicAdd(gen, 1);
        } else {
            while (atomicAdd(gen, 0) == g) __builtin_amdgcn_s_sleep(8);
        }
        __threadfence();                                   // acquire
    }
    __syncthreads();
}

__global__ __launch_bounds__(256, 2) void k_mega(
        const float* __restrict__ x, const float* __restrict__ Wq,
        const float* __restrict__ gamma, const float* __restrict__ beta,
        const float* __restrict__ Wp, const float* __restrict__ bp,
        short* __restrict__ xs, short* __restrict__ Wqd, short* __restrict__ Wpd,
        short* __restrict__ qkvb, unsigned char* __restrict__ qp,
        unsigned char* __restrict__ kp, unsigned char* __restrict__ vt,
        float* __restrict__ psum, float* __restrict__ psq,
        float* __restrict__ out, int* bar) {
    __shared__ __align__(16) unsigned char SM[54272];
    const int blk = blockIdx.x, tid = threadIdx.x;
    const int u = blk;
    const int lane = tid & 63, wv = tid >> 6;
    const int wy = wv >> 1, wx = wv & 1;
    const int quad = lane >> 4, l16 = lane & 15;
    int* cnt = bar;
    int* gen = bar + 16;
    short* sout = xs;                                   // xs dead after P1

    // ================= P0: prep =================
    {
        const int base = blk * 256 + tid;               // 131072 threads
        for (int i = base; i < 2097152; i += 131072)
            xs[i] = (short)f2bf(spikef(x[i]));
        for (int i = base; i < 786432; i += 131072)
            Wqd[i] = (short)(__builtin_bit_cast(unsigned int, Wq[i]) >> 16);
        for (int i = base; i < 262144; i += 131072)
            Wpd[i] = (short)(__builtin_bit_cast(unsigned int, Wp[i]) >> 16);
    }
    grid_barrier(cnt, gen);

    // ================= P1: qkv GEMM (K=512, 128x96 tiles, BK=64, XOR swizzle) =================
    {
        short* As = (short*)SM;          // 16 KB
        short* Bs = (short*)(SM + 16384);// 12 KB
        const int m0 = (u >> 4) * 128, n0 = (u & 15) * 96;
        const int K = 512, N = 1536;

        f32x4 acc[4][3];
        #pragma unroll
        for (int i = 0; i < 4; ++i)
            #pragma unroll
            for (int j = 0; j < 3; ++j)
                #pragma unroll
                for (int r = 0; r < 4; ++r) acc[i][j][r] = 0.f;

        const short* gA[4]; short* lA[4];
        #pragma unroll
        for (int i = 0; i < 4; ++i) {
            int L = wv + 4 * i;
            int c = L * 64 + lane;
            int r = c >> 3, g = (c & 7) ^ (r & 7);
            gA[i] = xs + (size_t)(m0 + r) * K + g * 8;
            lA[i] = &As[L * 512];
        }
        const short* gB[3]; short* lB[3];
        #pragma unroll
        for (int i = 0; i < 3; ++i) {
            int L = wv + 4 * i;
            int c = L * 64 + lane;
            int r = c >> 3, g = (c & 7) ^ (r & 7);
            gB[i] = Wqd + (size_t)(n0 + r) * K + g * 8;
            lB[i] = &Bs[L * 512];
        }

        for (int k0 = 0; k0 < K; k0 += 64) {
            __syncthreads();
            #pragma unroll
            for (int i = 0; i < 4; ++i) GLOAD_LDS16(gA[i] + k0, lA[i]);
            #pragma unroll
            for (int i = 0; i < 3; ++i) GLOAD_LDS16(gB[i] + k0, lB[i]);
            __syncthreads();
            #pragma unroll
            for (int sub = 0; sub < 2; ++sub) {
                const int jc = (sub * 4 + quad) ^ (l16 & 7);
                short8 aF[4], bF[3];
                #pragma unroll
                for (int mt = 0; mt < 4; ++mt)
                    aF[mt] = *(const short8*)&As[(wy * 64 + mt * 16 + l16) * 64 + jc * 8];
                #pragma unroll
                for (int nt = 0; nt < 3; ++nt)
                    bF[nt] = *(const short8*)&Bs[(wx * 48 + nt * 16 + l16) * 64 + jc * 8];
                #pragma unroll
                for (int mt = 0; mt < 4; ++mt)
                    #pragma unroll
                    for (int nt = 0; nt < 3; ++nt)
                        acc[mt][nt] = __builtin_amdgcn_mfma_f32_16x16x32_bf16(aF[mt], bF[nt], acc[mt][nt], 0, 0, 0);
            }
        }

        #pragma unroll
        for (int mt = 0; mt < 4; ++mt)
            #pragma unroll
            for (int r = 0; r < 4; ++r) {
                int row = m0 + wy * 64 + mt * 16 + quad * 4 + r;
                short* Cr = qkvb + (size_t)row * N + n0 + wx * 48 + l16;
                #pragma unroll
                for (int nt = 0; nt < 3; ++nt) Cr[nt * 16] = (short)f2bf_rn(acc[mt][nt][r]);
            }

        __syncthreads();
        float* PS = (float*)SM;
        float* PQ = (float*)(SM + 16384);
        #pragma unroll
        for (int nt = 0; nt < 3; ++nt) {
            float s = 0.f, q = 0.f;
            #pragma unroll
            for (int mt = 0; mt < 4; ++mt)
                #pragma unroll
                for (int r = 0; r < 4; ++r) {
                    float v = acc[mt][nt][r];
                    s += v;
                    q = fmaf(v, v, q);
                }
            PS[(wy * 4 + quad) * 96 + wx * 48 + nt * 16 + l16] = s;
            PQ[(wy * 4 + quad) * 96 + wx * 48 + nt * 16 + l16] = q;
        }
        __syncthreads();
        if (tid < 96) {
            float s = 0.f, q = 0.f;
            #pragma unroll
            for (int i = 0; i < 8; ++i) { s += PS[i * 96 + tid]; q += PQ[i * 96 + tid]; }
            psum[(u >> 4) * 1536 + n0 + tid] = s;
            psq [(u >> 4) * 1536 + n0 + tid] = q;
        }
    }
    grid_barrier(cnt, gen);

    // ================= P2: BN finalize + spike + pack (384 active blocks) =================
    if (u < 384) {
        float* sa = (float*)SM;                 // 64 floats
        float* sb = (float*)(SM + 256);
        unsigned char* tile = SM + 512;         // 64*80
        const int slice = u % 24;
        const int r0 = (u / 24) * 256;
        const int c0 = slice * 64;
        const int b = r0 >> 10, nb = r0 & 1023;

        if (tid < 64) {
            const int c = c0 + tid;
            double s = 0.0, q = 0.0;
            for (int st = 0; st < 32; ++st) { s += (double)psum[st * 1536 + c]; q += (double)psq[st * 1536 + c]; }
            const double mu  = s / 4096.0;
            const double var = q / 4096.0 - mu * mu;
            const float a = (float)((double)gamma[c] / sqrt(var + 1e-5));
            sa[tid] = a;
            sb[tid] = fmaf(-(float)mu, a, beta[c]);
        }
        __syncthreads();

        const int ch = tid & 63, rq = tid >> 6;
        const float A = sa[ch], Bsh = sb[ch];

        if (slice < 16) {
            const int h = slice & 7;
            unsigned char* base = (slice < 8 ? qp : kp) + (((size_t)b * 8 + h) * 1024 + nb) * 64;
            for (int i = rq; i < 256; i += 4) {
                float v = bf2f((unsigned short)qkvb[(size_t)(r0 + i) * 1536 + c0 + ch]);
                base[(size_t)i * 64 + ch] = (unsigned char)spikef(fmaf(v, A, Bsh));
            }
        } else {
            const int h = slice - 16;
            const int e = tid >> 2, j0 = (tid & 3) * 16;
            unsigned char* vbase = vt + (((size_t)b * 8 + h) * 64 + e) * 1024 + nb;
            for (int rb = 0; rb < 4; ++rb) {
                __syncthreads();
                for (int i = rq; i < 64; i += 4) {
                    float v = bf2f((unsigned short)qkvb[(size_t)(r0 + rb * 64 + i) * 1536 + c0 + ch]);
                    tile[ch * 80 + i] = (unsigned char)spikef(fmaf(v, A, Bsh));
                }
                __syncthreads();
                *(u32x4*)&vbase[rb * 64 + j0] = *(const u32x4*)&tile[e * 80 + j0];
            }
        }
    }
    grid_barrier(cnt, gen);

    // ================= P3: i8-MFMA attention (256-wide j-tiles) =================
    {
        unsigned char* Qs = SM;                         // 64 x 64B
        unsigned char* Ks = SM + 4096;                  // 256 x 64B
        unsigned char* Vs = SM + 20480;                 // 64 x 256B
        unsigned int* Sb = (unsigned int*)(SM + 36864); // 64 x 68 dw
        const int b = u >> 7, h = (u >> 4) & 7;
        const int n0 = (u & 15) * 64;
        const size_t bh = (size_t)b * 8 + h;

        {
            const int r = tid >> 2, p = tid & 3;
            const int g = p ^ (r & 3) ^ ((r >> 2) & 3);
            GLOAD_LDS16(qp + (bh * 1024 + n0 + r) * 64 + g * 16, Qs + (size_t)tid * 16);
        }
        const unsigned char* gK[4]; unsigned char* lK[4];
        const unsigned char* gV[4]; unsigned char* lV[4];
        #pragma unroll
        for (int i = 0; i < 4; ++i) {
            int c = tid + 256 * i;
            int rk = c >> 2, pk2 = c & 3;
            int gk = pk2 ^ (rk & 3) ^ ((rk >> 2) & 3);
            gK[i] = kp + (bh * 1024 + rk) * 64 + gk * 16;
            lK[i] = Ks + (size_t)c * 16;
            int rv = c >> 4, pv = c & 15;
            int gv = pv ^ (rv & 15);
            gV[i] = vt + (bh * 64 + rv) * 1024 + gv * 16;
            lV[i] = Vs + (size_t)c * 16;
        }
        __syncthreads();
        u32x4 qf[4];
        {
            const int pq = quad ^ (l16 & 3) ^ ((l16 >> 2) & 3);
            #pragma unroll
            for (int mt = 0; mt < 4; ++mt)
                qf[mt] = *(const u32x4*)&Qs[(mt * 16 + l16) * 64 + pq * 16];
        }

        int4v of[4];
        #pragma unroll
        for (int mt = 0; mt < 4; ++mt)
            #pragma unroll
            for (int r = 0; r < 4; ++r) of[mt][r] = 0;

        const int pk = quad ^ (l16 & 3) ^ ((l16 >> 2) & 3);

        for (int j0 = 0; j0 < 1024; j0 += 256) {
            __syncthreads();
            #pragma unroll
            for (int i = 0; i < 4; ++i) {
                GLOAD_LDS16(gK[i] + (size_t)j0 * 64, lK[i]);
                GLOAD_LDS16(gV[i] + j0, lV[i]);
            }
            __syncthreads();

            #pragma unroll
            for (int jt = 0; jt < 4; ++jt) {
                u32x4 kf = *(const u32x4*)&Ks[(wv * 64 + jt * 16 + l16) * 64 + pk * 16];
                #pragma unroll
                for (int mt = 0; mt < 4; ++mt) {
                    int4v z;
                    #pragma unroll
                    for (int r = 0; r < 4; ++r) z[r] = 0;
                    int4v s = mfma_i8(kf, qf[mt], z);
                    unsigned int pkk = 0;
                    #pragma unroll
                    for (int r = 0; r < 4; ++r) {
                        int v = s[r]; v = v < 0 ? 0 : (v > 4 ? 4 : v);
                        pkk |= (unsigned int)v << (8 * r);
                    }
                    Sb[(mt * 16 + l16) * 68 + wv * 16 + jt * 4 + quad] = pkk;
                }
            }
            __syncthreads();

            #pragma unroll
            for (int kk = 0; kk < 4; ++kk) {
                const int pv = (kk * 4 + quad) ^ l16;
                u32x4 bV = *(const u32x4*)&Vs[(wv * 16 + l16) * 256 + pv * 16];
                #pragma unroll
                for (int mt = 0; mt < 4; ++mt) {
                    u32x4 aS = *(const u32x4*)&Sb[(mt * 16 + l16) * 68 + kk * 16 + quad * 4];
                    of[mt] = mfma_i8(aS, bV, of[mt]);
                }
            }
        }

        #pragma unroll
        for (int mt = 0; mt < 4; ++mt)
            #pragma unroll
            for (int r = 0; r < 4; ++r) {
                size_t orow = (size_t)b * 1024 + n0 + mt * 16 + quad * 4 + r;
                sout[orow * 512 + h * 64 + wv * 16 + l16] =
                    (short)f2bf(spikef((float)of[mt][r] * 0.125f));
            }
    }
    grid_barrier(cnt, gen);

    // ================= P4: proj GEMM (M=4096 N=512 K=512, BM=32 BN=128) =================
    {
        short* As = (short*)SM;          // 32*32 shorts
        short* Bs = (short*)(SM + 2048); // 128*32 shorts
        const int m0 = (u >> 2) * 32, n0 = (u & 3) * 128;
        const int K = 512, N = 512;

        f32x4 acc[1][4];
        #pragma unroll
        for (int j = 0; j < 4; ++j)
            #pragma unroll
            for (int r = 0; r < 4; ++r) acc[0][j][r] = 0.f;

        const short* gA0 = nullptr; short* lA0 = nullptr;
        {
            int L = wv;
            if (L < 2) {
                int c = L * 64 + lane;
                gA0 = sout + (size_t)(m0 + (c >> 2)) * K + (c & 3) * 8;
                lA0 = &As[L * 512];
            }
        }
        const short* gB[2]; short* lB[2];
        #pragma unroll
        for (int i = 0; i < 2; ++i) {
            int L = wv + 4 * i;
            int c = L * 64 + lane;
            gB[i] = Wpd + (size_t)(n0 + (c >> 2)) * K + (c & 3) * 8;
            lB[i] = &Bs[L * 512];
        }

        for (int k0 = 0; k0 < K; k0 += 32) {
            __syncthreads();
            if (gA0) GLOAD_LDS16(gA0 + k0, lA0);
            #pragma unroll
            for (int i = 0; i < 2; ++i) GLOAD_LDS16(gB[i] + k0, lB[i]);
            __syncthreads();
            short8 aF, bF[4];
            aF = *(const short8*)&As[(wy * 16 + l16) * 32 + quad * 8];
            #pragma unroll
            for (int nt = 0; nt < 4; ++nt)
                bF[nt] = *(const short8*)&Bs[(wx * 64 + nt * 16 + l16) * 32 + quad * 8];
            #pragma unroll
            for (int nt = 0; nt < 4; ++nt)
                acc[0][nt] = __builtin_amdgcn_mfma_f32_16x16x32_bf16(aF, bF[nt], acc[0][nt], 0, 0, 0);
        }

        float bs[4];
        #pragma unroll
        for (int nt = 0; nt < 4; ++nt) bs[nt] = bp[n0 + wx * 64 + nt * 16 + l16];
        #pragma unroll
        for (int r = 0; r < 4; ++r) {
            int row = m0 + wy * 16 + quad * 4 + r;
            float* Cr = out + (size_t)row * N + n0 + wx * 64 + l16;
            #pragma unroll
            for (int nt = 0; nt < 4; ++nt) Cr[nt * 16] = acc[0][nt][r] + bs[nt];
        }
    }
}

extern "C" void kernel_launch(void* const* d_in, const int* in_sizes, int n_in,
                              void* d_out, int out_size, void* d_ws, size_t ws_size,
                              hipStream_t stream) {
    const float* x     = (const float*)d_in[0];
    const float* Wqkv  = (const float*)d_in[1];
    const float* gamma = (const float*)d_in[2];
    const float* beta  = (const float*)d_in[3];
    const float* Wproj = (const float*)d_in[4];
    const float* bproj = (const float*)d_in[5];
    float* out = (float*)d_out;

    char* w = (char*)d_ws;
    short* xs            = (short*)(w);                     // 4 MB; reused as sout
    short* Wqkv2         = (short*)(w + 8388608);           // 1.5 MB
    short* Wproj2        = (short*)(w + 11534336);          // 0.5 MB
    short* qkvb          = (short*)(w + 12582912);          // 12 MB
    unsigned char* qp    = (unsigned char*)(w + 37748736);  // 2 MB
    unsigned char* kp    = (unsigned char*)(w + 41943040);  // 2 MB
    unsigned char* vt    = (unsigned char*)(w + 46137344);  // 2 MB
    float* psum          = (float*)(w + 50331648);
    float* psq           = psum + 32 * 1536;
    int*   bar           = (int*)(w + 60817408);            // 2 ints (cnt @0, gen @64B)

    hipMemsetAsync(bar, 0, 128, stream);
    k_mega<<<NB, 256, 0, stream>>>(x, Wqkv, gamma, beta, Wproj, bproj,
                                   xs, Wqkv2, Wproj2, qkvb, qp, kp, vt,
                                   psum, psq, out, bar);
}

// Round 13
// 320.229 us; speedup vs baseline: 1.0024x; 1.0024x over previous
//
#include <hip/hip_runtime.h>

typedef __attribute__((ext_vector_type(8))) short short8;
typedef __attribute__((ext_vector_type(4))) float f32x4;
typedef __attribute__((ext_vector_type(4))) int int4v;
typedef __attribute__((ext_vector_type(4))) unsigned int u32x4;

#define THRE 4.0f

#define GLOAD_LDS16(g, l) \
    __builtin_amdgcn_global_load_lds((const __attribute__((address_space(1))) void*)(g), \
                                     (__attribute__((address_space(3))) void*)(l), 16, 0, 0)

__device__ __forceinline__ float spikef(float x) {
    return floorf(fminf(fmaxf(x, 0.0f), THRE) + 0.5f);
}
__device__ __forceinline__ unsigned short f2bf(float f) {
    return (unsigned short)(__builtin_bit_cast(unsigned int, f) >> 16);
}
__device__ __forceinline__ unsigned short f2bf_rn(float f) {
    unsigned u = __builtin_bit_cast(unsigned int, f);
    unsigned r = ((u >> 16) & 1u) + 0x7FFFu;
    return (unsigned short)((u + r) >> 16);
}
__device__ __forceinline__ float bf2f(unsigned short s) {
    return __builtin_bit_cast(float, (unsigned int)s << 16);
}
__device__ __forceinline__ int4v mfma_i8(u32x4 a, u32x4 b, int4v c) {
    return __builtin_amdgcn_mfma_i32_16x16x64_i8(__builtin_bit_cast(int4v, a),
                                                 __builtin_bit_cast(int4v, b), c, 0, 0, 0);
}

#define NB 512

// grid barrier, one counter per phase (no reset -> no reset/arrival race).
// Arrive: single RMW per block (release). Spin: plain coherent LOADS (no RMW storm).
__device__ __forceinline__ void grid_barrier(int* c) {
    __syncthreads();
    if (threadIdx.x == 0) {
        __threadfence();
        __hip_atomic_fetch_add(c, 1, __ATOMIC_ACQ_REL, __HIP_MEMORY_SCOPE_AGENT);
        while (__hip_atomic_load(c, __ATOMIC_ACQUIRE, __HIP_MEMORY_SCOPE_AGENT) < NB)
            __builtin_amdgcn_s_sleep(32);
    }
    __syncthreads();
}

__global__ __launch_bounds__(256, 2) void k_mega(
        const float* __restrict__ x, const float* __restrict__ Wq,
        const float* __restrict__ gamma, const float* __restrict__ beta,
        const float* __restrict__ Wp, const float* __restrict__ bp,
        short* __restrict__ xs, short* __restrict__ Wqd, short* __restrict__ Wpd,
        short* __restrict__ qkvb, unsigned char* __restrict__ qp,
        unsigned char* __restrict__ kp, unsigned char* __restrict__ vt,
        float* __restrict__ psum, float* __restrict__ psq,
        float* __restrict__ out, int* bar) {
    __shared__ __align__(16) unsigned char SM[54272];
    const int blk = blockIdx.x, tid = threadIdx.x;
    const int u = blk;
    const int lane = tid & 63, wv = tid >> 6;
    const int wy = wv >> 1, wx = wv & 1;
    const int quad = lane >> 4, l16 = lane & 15;
    short* sout = xs;                                   // xs dead after P1

    // ================= P0: prep =================
    {
        const int base = blk * 256 + tid;               // 131072 threads
        for (int i = base; i < 2097152; i += 131072)
            xs[i] = (short)f2bf(spikef(x[i]));
        for (int i = base; i < 786432; i += 131072)
            Wqd[i] = (short)(__builtin_bit_cast(unsigned int, Wq[i]) >> 16);
        for (int i = base; i < 262144; i += 131072)
            Wpd[i] = (short)(__builtin_bit_cast(unsigned int, Wp[i]) >> 16);
    }
    grid_barrier(bar);

    // ================= P1: qkv GEMM (K=512, 128x96 tiles, BK=64, XOR swizzle) =================
    {
        short* As = (short*)SM;          // 16 KB
        short* Bs = (short*)(SM + 16384);// 12 KB
        const int m0 = (u >> 4) * 128, n0 = (u & 15) * 96;
        const int K = 512, N = 1536;

        f32x4 acc[4][3];
        #pragma unroll
        for (int i = 0; i < 4; ++i)
            #pragma unroll
            for (int j = 0; j < 3; ++j)
                #pragma unroll
                for (int r = 0; r < 4; ++r) acc[i][j][r] = 0.f;

        const short* gA[4]; short* lA[4];
        #pragma unroll
        for (int i = 0; i < 4; ++i) {
            int L = wv + 4 * i;
            int c = L * 64 + lane;
            int r = c >> 3, g = (c & 7) ^ (r & 7);
            gA[i] = xs + (size_t)(m0 + r) * K + g * 8;
            lA[i] = &As[L * 512];
        }
        const short* gB[3]; short* lB[3];
        #pragma unroll
        for (int i = 0; i < 3; ++i) {
            int L = wv + 4 * i;
            int c = L * 64 + lane;
            int r = c >> 3, g = (c & 7) ^ (r & 7);
            gB[i] = Wqd + (size_t)(n0 + r) * K + g * 8;
            lB[i] = &Bs[L * 512];
        }

        for (int k0 = 0; k0 < K; k0 += 64) {
            __syncthreads();
            #pragma unroll
            for (int i = 0; i < 4; ++i) GLOAD_LDS16(gA[i] + k0, lA[i]);
            #pragma unroll
            for (int i = 0; i < 3; ++i) GLOAD_LDS16(gB[i] + k0, lB[i]);
            __syncthreads();
            #pragma unroll
            for (int sub = 0; sub < 2; ++sub) {
                const int jc = (sub * 4 + quad) ^ (l16 & 7);
                short8 aF[4], bF[3];
                #pragma unroll
                for (int mt = 0; mt < 4; ++mt)
                    aF[mt] = *(const short8*)&As[(wy * 64 + mt * 16 + l16) * 64 + jc * 8];
                #pragma unroll
                for (int nt = 0; nt < 3; ++nt)
                    bF[nt] = *(const short8*)&Bs[(wx * 48 + nt * 16 + l16) * 64 + jc * 8];
                #pragma unroll
                for (int mt = 0; mt < 4; ++mt)
                    #pragma unroll
                    for (int nt = 0; nt < 3; ++nt)
                        acc[mt][nt] = __builtin_amdgcn_mfma_f32_16x16x32_bf16(aF[mt], bF[nt], acc[mt][nt], 0, 0, 0);
            }
        }

        #pragma unroll
        for (int mt = 0; mt < 4; ++mt)
            #pragma unroll
            for (int r = 0; r < 4; ++r) {
                int row = m0 + wy * 64 + mt * 16 + quad * 4 + r;
                short* Cr = qkvb + (size_t)row * N + n0 + wx * 48 + l16;
                #pragma unroll
                for (int nt = 0; nt < 3; ++nt) Cr[nt * 16] = (short)f2bf_rn(acc[mt][nt][r]);
            }

        __syncthreads();
        float* PS = (float*)SM;
        float* PQ = (float*)(SM + 16384);
        #pragma unroll
        for (int nt = 0; nt < 3; ++nt) {
            float s = 0.f, q = 0.f;
            #pragma unroll
            for (int mt = 0; mt < 4; ++mt)
                #pragma unroll
                for (int r = 0; r < 4; ++r) {
                    float v = acc[mt][nt][r];
                    s += v;
                    q = fmaf(v, v, q);
                }
            PS[(wy * 4 + quad) * 96 + wx * 48 + nt * 16 + l16] = s;
            PQ[(wy * 4 + quad) * 96 + wx * 48 + nt * 16 + l16] = q;
        }
        __syncthreads();
        if (tid < 96) {
            float s = 0.f, q = 0.f;
            #pragma unroll
            for (int i = 0; i < 8; ++i) { s += PS[i * 96 + tid]; q += PQ[i * 96 + tid]; }
            psum[(u >> 4) * 1536 + n0 + tid] = s;
            psq [(u >> 4) * 1536 + n0 + tid] = q;
        }
    }
    grid_barrier(bar + 16);

    // ================= P2: BN finalize + spike + pack (384 active blocks) =================
    if (u < 384) {
        float* sa = (float*)SM;                 // 64 floats
        float* sb = (float*)(SM + 256);
        unsigned char* tile = SM + 512;         // 64*80
        const int slice = u % 24;
        const int r0 = (u / 24) * 256;
        const int c0 = slice * 64;
        const int b = r0 >> 10, nb = r0 & 1023;

        if (tid < 64) {
            const int c = c0 + tid;
            double s = 0.0, q = 0.0;
            for (int st = 0; st < 32; ++st) { s += (double)psum[st * 1536 + c]; q += (double)psq[st * 1536 + c]; }
            const double mu  = s / 4096.0;
            const double var = q / 4096.0 - mu * mu;
            const float a = (float)((double)gamma[c] / sqrt(var + 1e-5));
            sa[tid] = a;
            sb[tid] = fmaf(-(float)mu, a, beta[c]);
        }
        __syncthreads();

        const int ch = tid & 63, rq = tid >> 6;
        const float A = sa[ch], Bsh = sb[ch];

        if (slice < 16) {
            const int h = slice & 7;
            unsigned char* base = (slice < 8 ? qp : kp) + (((size_t)b * 8 + h) * 1024 + nb) * 64;
            for (int i = rq; i < 256; i += 4) {
                float v = bf2f((unsigned short)qkvb[(size_t)(r0 + i) * 1536 + c0 + ch]);
                base[(size_t)i * 64 + ch] = (unsigned char)spikef(fmaf(v, A, Bsh));
            }
        } else {
            const int h = slice - 16;
            const int e = tid >> 2, j0 = (tid & 3) * 16;
            unsigned char* vbase = vt + (((size_t)b * 8 + h) * 64 + e) * 1024 + nb;
            for (int rb = 0; rb < 4; ++rb) {
                __syncthreads();
                for (int i = rq; i < 64; i += 4) {
                    float v = bf2f((unsigned short)qkvb[(size_t)(r0 + rb * 64 + i) * 1536 + c0 + ch]);
                    tile[ch * 80 + i] = (unsigned char)spikef(fmaf(v, A, Bsh));
                }
                __syncthreads();
                *(u32x4*)&vbase[rb * 64 + j0] = *(const u32x4*)&tile[e * 80 + j0];
            }
        }
    }
    grid_barrier(bar + 32);

    // ================= P3: i8-MFMA attention (256-wide j-tiles) =================
    {
        unsigned char* Qs = SM;                         // 64 x 64B
        unsigned char* Ks = SM + 4096;                  // 256 x 64B
        unsigned char* Vs = SM + 20480;                 // 64 x 256B
        unsigned int* Sb = (unsigned int*)(SM + 36864); // 64 x 68 dw
        const int b = u >> 7, h = (u >> 4) & 7;
        const int n0 = (u & 15) * 64;
        const size_t bh = (size_t)b * 8 + h;

        {
            const int r = tid >> 2, p = tid & 3;
            const int g = p ^ (r & 3) ^ ((r >> 2) & 3);
            GLOAD_LDS16(qp + (bh * 1024 + n0 + r) * 64 + g * 16, Qs + (size_t)tid * 16);
        }
        const unsigned char* gK[4]; unsigned char* lK[4];
        const unsigned char* gV[4]; unsigned char* lV[4];
        #pragma unroll
        for (int i = 0; i < 4; ++i) {
            int c = tid + 256 * i;
            int rk = c >> 2, pk2 = c & 3;
            int gk = pk2 ^ (rk & 3) ^ ((rk >> 2) & 3);
            gK[i] = kp + (bh * 1024 + rk) * 64 + gk * 16;
            lK[i] = Ks + (size_t)c * 16;
            int rv = c >> 4, pv = c & 15;
            int gv = pv ^ (rv & 15);
            gV[i] = vt + (bh * 64 + rv) * 1024 + gv * 16;
            lV[i] = Vs + (size_t)c * 16;
        }
        __syncthreads();
        u32x4 qf[4];
        {
            const int pq = quad ^ (l16 & 3) ^ ((l16 >> 2) & 3);
            #pragma unroll
            for (int mt = 0; mt < 4; ++mt)
                qf[mt] = *(const u32x4*)&Qs[(mt * 16 + l16) * 64 + pq * 16];
        }

        int4v of[4];
        #pragma unroll
        for (int mt = 0; mt < 4; ++mt)
            #pragma unroll
            for (int r = 0; r < 4; ++r) of[mt][r] = 0;

        const int pk = quad ^ (l16 & 3) ^ ((l16 >> 2) & 3);

        for (int j0 = 0; j0 < 1024; j0 += 256) {
            __syncthreads();
            #pragma unroll
            for (int i = 0; i < 4; ++i) {
                GLOAD_LDS16(gK[i] + (size_t)j0 * 64, lK[i]);
                GLOAD_LDS16(gV[i] + j0, lV[i]);
            }
            __syncthreads();

            #pragma unroll
            for (int jt = 0; jt < 4; ++jt) {
                u32x4 kf = *(const u32x4*)&Ks[(wv * 64 + jt * 16 + l16) * 64 + pk * 16];
                #pragma unroll
                for (int mt = 0; mt < 4; ++mt) {
                    int4v z;
                    #pragma unroll
                    for (int r = 0; r < 4; ++r) z[r] = 0;
                    int4v s = mfma_i8(kf, qf[mt], z);
                    unsigned int pkk = 0;
                    #pragma unroll
                    for (int r = 0; r < 4; ++r) {
                        int v = s[r]; v = v < 0 ? 0 : (v > 4 ? 4 : v);
                        pkk |= (unsigned int)v << (8 * r);
                    }
                    Sb[(mt * 16 + l16) * 68 + wv * 16 + jt * 4 + quad] = pkk;
                }
            }
            __syncthreads();

            #pragma unroll
            for (int kk = 0; kk < 4; ++kk) {
                const int pv = (kk * 4 + quad) ^ l16;
                u32x4 bV = *(const u32x4*)&Vs[(wv * 16 + l16) * 256 + pv * 16];
                #pragma unroll
                for (int mt = 0; mt < 4; ++mt) {
                    u32x4 aS = *(const u32x4*)&Sb[(mt * 16 + l16) * 68 + kk * 16 + quad * 4];
                    of[mt] = mfma_i8(aS, bV, of[mt]);
                }
            }
        }

        #pragma unroll
        for (int mt = 0; mt < 4; ++mt)
            #pragma unroll
            for (int r = 0; r < 4; ++r) {
                size_t orow = (size_t)b * 1024 + n0 + mt * 16 + quad * 4 + r;
                sout[orow * 512 + h * 64 + wv * 16 + l16] =
                    (short)f2bf(spikef((float)of[mt][r] * 0.125f));
            }
    }
    grid_barrier(bar + 48);

    // ================= P4: proj GEMM (M=4096 N=512 K=512, BM=32 BN=128) =================
    {
        short* As = (short*)SM;          // 32*32 shorts
        short* Bs = (short*)(SM + 2048); // 128*32 shorts
        const int m0 = (u >> 2) * 32, n0 = (u & 3) * 128;
        const int K = 512, N = 512;

        f32x4 acc[1][4];
        #pragma unroll
        for (int j = 0; j < 4; ++j)
            #pragma unroll
            for (int r = 0; r < 4; ++r) acc[0][j][r] = 0.f;

        const short* gA0 = nullptr; short* lA0 = nullptr;
        {
            int L = wv;
            if (L < 2) {
                int c = L * 64 + lane;
                gA0 = sout + (size_t)(m0 + (c >> 2)) * K + (c & 3) * 8;
                lA0 = &As[L * 512];
            }
        }
        const short* gB[2]; short* lB[2];
        #pragma unroll
        for (int i = 0; i < 2; ++i) {
            int L = wv + 4 * i;
            int c = L * 64 + lane;
            gB[i] = Wpd + (size_t)(n0 + (c >> 2)) * K + (c & 3) * 8;
            lB[i] = &Bs[L * 512];
        }

        for (int k0 = 0; k0 < K; k0 += 32) {
            __syncthreads();
            if (gA0) GLOAD_LDS16(gA0 + k0, lA0);
            #pragma unroll
            for (int i = 0; i < 2; ++i) GLOAD_LDS16(gB[i] + k0, lB[i]);
            __syncthreads();
            short8 aF, bF[4];
            aF = *(const short8*)&As[(wy * 16 + l16) * 32 + quad * 8];
            #pragma unroll
            for (int nt = 0; nt < 4; ++nt)
                bF[nt] = *(const short8*)&Bs[(wx * 64 + nt * 16 + l16) * 32 + quad * 8];
            #pragma unroll
            for (int nt = 0; nt < 4; ++nt)
                acc[0][nt] = __builtin_amdgcn_mfma_f32_16x16x32_bf16(aF, bF[nt], acc[0][nt], 0, 0, 0);
        }

        float bs[4];
        #pragma unroll
        for (int nt = 0; nt < 4; ++nt) bs[nt] = bp[n0 + wx * 64 + nt * 16 + l16];
        #pragma unroll
        for (int r = 0; r < 4; ++r) {
            int row = m0 + wy * 16 + quad * 4 + r;
            float* Cr = out + (size_t)row * N + n0 + wx * 64 + l16;
            #pragma unroll
            for (int nt = 0; nt < 4; ++nt) Cr[nt * 16] = acc[0][nt][r] + bs[nt];
        }
    }
}

extern "C" void kernel_launch(void* const* d_in, const int* in_sizes, int n_in,
                              void* d_out, int out_size, void* d_ws, size_t ws_size,
                              hipStream_t stream) {
    const float* x     = (const float*)d_in[0];
    const float* Wqkv  = (const float*)d_in[1];
    const float* gamma = (const float*)d_in[2];
    const float* beta  = (const float*)d_in[3];
    const float* Wproj = (const float*)d_in[4];
    const float* bproj = (const float*)d_in[5];
    float* out = (float*)d_out;

    char* w = (char*)d_ws;
    short* xs            = (short*)(w);                     // 4 MB; reused as sout
    short* Wqkv2         = (short*)(w + 8388608);           // 1.5 MB
    short* Wproj2        = (short*)(w + 11534336);          // 0.5 MB
    short* qkvb          = (short*)(w + 12582912);          // 12 MB
    unsigned char* qp    = (unsigned char*)(w + 37748736);  // 2 MB
    unsigned char* kp    = (unsigned char*)(w + 41943040);  // 2 MB
    unsigned char* vt    = (unsigned char*)(w + 46137344);  // 2 MB
    float* psum          = (float*)(w + 50331648);
    float* psq           = psum + 32 * 1536;
    int*   bar           = (int*)(w + 60817408);            // 4 counters, 64B apart

    hipMemsetAsync(bar, 0, 512, stream);
    k_mega<<<NB, 256, 0, stream>>>(x, Wqkv, gamma, beta, Wproj, bproj,
                                   xs, Wqkv2, Wproj2, qkvb, qp, kp, vt,
                                   psum, psq, out, bar);
}

// Round 14
// 116.055 us; speedup vs baseline: 2.7660x; 2.7593x over previous
//
#include <hip/hip_runtime.h>

typedef __attribute__((ext_vector_type(8))) short short8;
typedef __attribute__((ext_vector_type(4))) short short4v;
typedef __attribute__((ext_vector_type(4))) float f32x4;
typedef __attribute__((ext_vector_type(4))) int int4v;
typedef __attribute__((ext_vector_type(4))) unsigned int u32x4;

#define THRE 4.0f

#define GLOAD_LDS16(g, l) \
    __builtin_amdgcn_global_load_lds((const __attribute__((address_space(1))) void*)(g), \
                                     (__attribute__((address_space(3))) void*)(l), 16, 0, 0)

__device__ __forceinline__ float spikef(float x) {
    return floorf(fminf(fmaxf(x, 0.0f), THRE) + 0.5f);
}
__device__ __forceinline__ unsigned short f2bf(float f) {   // truncate; exact for small ints
    return (unsigned short)(__builtin_bit_cast(unsigned int, f) >> 16);
}
__device__ __forceinline__ unsigned short f2bf_rn(float f) { // round-to-nearest
    unsigned u = __builtin_bit_cast(unsigned int, f);
    unsigned r = ((u >> 16) & 1u) + 0x7FFFu;
    return (unsigned short)((u + r) >> 16);
}
__device__ __forceinline__ float bf2f(unsigned short s) {
    return __builtin_bit_cast(float, (unsigned int)s << 16);
}
__device__ __forceinline__ int4v mfma_i8(u32x4 a, u32x4 b, int4v c) {
    return __builtin_amdgcn_mfma_i32_16x16x64_i8(__builtin_bit_cast(int4v, a),
                                                 __builtin_bit_cast(int4v, b), c, 0, 0, 0);
}

// ---------- prep (x4 vectorized): spike(x)->bf16; Wqkv/Wproj -> bf16 hi ----------
__global__ void k_prep(const float* __restrict__ x,
                       const float* __restrict__ Wq, const float* __restrict__ Wp,
                       short* __restrict__ xs, short* __restrict__ Wqd, short* __restrict__ Wpd) {
    int i = blockIdx.x * 256 + threadIdx.x;             // 3072 blocks = 786432 threads
    if (i < 524288) {                                    // x: 2097152 floats
        const float4 v = *(const float4*)&x[(size_t)i * 4];
        short4v o;
        o.x = (short)f2bf(spikef(v.x));
        o.y = (short)f2bf(spikef(v.y));
        o.z = (short)f2bf(spikef(v.z));
        o.w = (short)f2bf(spikef(v.w));
        *(short4v*)&xs[(size_t)i * 4] = o;
    } else if (i < 720896) {                             // Wqkv: 786432 floats
        const size_t j = (size_t)(i - 524288) * 4;
        const float4 v = *(const float4*)&Wq[j];
        short4v o;
        o.x = (short)(__builtin_bit_cast(unsigned int, v.x) >> 16);
        o.y = (short)(__builtin_bit_cast(unsigned int, v.y) >> 16);
        o.z = (short)(__builtin_bit_cast(unsigned int, v.z) >> 16);
        o.w = (short)(__builtin_bit_cast(unsigned int, v.w) >> 16);
        *(short4v*)&Wqd[j] = o;
    } else {                                             // Wproj: 262144 floats
        const size_t j = (size_t)(i - 720896) * 4;
        const float4 v = *(const float4*)&Wp[j];
        short4v o;
        o.x = (short)(__builtin_bit_cast(unsigned int, v.x) >> 16);
        o.y = (short)(__builtin_bit_cast(unsigned int, v.y) >> 16);
        o.z = (short)(__builtin_bit_cast(unsigned int, v.z) >> 16);
        o.w = (short)(__builtin_bit_cast(unsigned int, v.w) >> 16);
        *(short4v*)&Wpd[j] = o;
    }
}

// ---------- qkv GEMM: M=4096 N=1536 K=512, BM=128 BN=96 BK=64; bf16 out ----------
// Flat grid 512, XCD-swizzled: u = ntile*32 + mtile -> same A-stripe on same XCD.
__global__ __launch_bounds__(256) void k_gemm_qkv(const short* __restrict__ A,
                                                  const short* __restrict__ B,
                                                  short* __restrict__ C,
                                                  float* __restrict__ psum,
                                                  float* __restrict__ psq) {
    __shared__ __align__(16) short As[128 * 64];
    __shared__ __align__(16) short Bs[96 * 64];
    const int tid  = threadIdx.x;
    const int lane = tid & 63, wv = tid >> 6;
    const int wy = wv >> 1, wx = wv & 1;
    const int quad = lane >> 4, l16 = lane & 15;
    const int u = blockIdx.x;
    const int mtile = u & 31;                      // XCD = u%8 = mtile%8
    const int m0 = mtile * 128, n0 = (u >> 5) * 96;
    const int K = 512, N = 1536;

    f32x4 acc[4][3];
    #pragma unroll
    for (int i = 0; i < 4; ++i)
        #pragma unroll
        for (int j = 0; j < 3; ++j)
            #pragma unroll
            for (int r = 0; r < 4; ++r) acc[i][j][r] = 0.f;

    const short* gA[4]; short* lA[4];
    #pragma unroll
    for (int i = 0; i < 4; ++i) {
        int L = wv + 4 * i;
        int c = L * 64 + lane;
        int r = c >> 3, g = (c & 7) ^ (r & 7);
        gA[i] = A + (size_t)(m0 + r) * K + g * 8;
        lA[i] = &As[L * 512];
    }
    const short* gB[3]; short* lB[3];
    #pragma unroll
    for (int i = 0; i < 3; ++i) {
        int L = wv + 4 * i;
        int c = L * 64 + lane;
        int r = c >> 3, g = (c & 7) ^ (r & 7);
        gB[i] = B + (size_t)(n0 + r) * K + g * 8;
        lB[i] = &Bs[L * 512];
    }

    for (int k0 = 0; k0 < K; k0 += 64) {
        __syncthreads();
        #pragma unroll
        for (int i = 0; i < 4; ++i) GLOAD_LDS16(gA[i] + k0, lA[i]);
        #pragma unroll
        for (int i = 0; i < 3; ++i) GLOAD_LDS16(gB[i] + k0, lB[i]);
        __syncthreads();
        #pragma unroll
        for (int sub = 0; sub < 2; ++sub) {
            const int jc = (sub * 4 + quad) ^ (l16 & 7);
            short8 aF[4], bF[3];
            #pragma unroll
            for (int mt = 0; mt < 4; ++mt)
                aF[mt] = *(const short8*)&As[(wy * 64 + mt * 16 + l16) * 64 + jc * 8];
            #pragma unroll
            for (int nt = 0; nt < 3; ++nt)
                bF[nt] = *(const short8*)&Bs[(wx * 48 + nt * 16 + l16) * 64 + jc * 8];
            #pragma unroll
            for (int mt = 0; mt < 4; ++mt)
                #pragma unroll
                for (int nt = 0; nt < 3; ++nt)
                    acc[mt][nt] = __builtin_amdgcn_mfma_f32_16x16x32_bf16(aF[mt], bF[nt], acc[mt][nt], 0, 0, 0);
        }
    }

    #pragma unroll
    for (int mt = 0; mt < 4; ++mt)
        #pragma unroll
        for (int r = 0; r < 4; ++r) {
            int row = m0 + wy * 64 + mt * 16 + quad * 4 + r;
            short* Cr = C + (size_t)row * N + n0 + wx * 48 + l16;
            #pragma unroll
            for (int nt = 0; nt < 3; ++nt) Cr[nt * 16] = (short)f2bf_rn(acc[mt][nt][r]);
        }

    __syncthreads();
    float* PS = (float*)As;   // [8][96]
    float* PQ = (float*)Bs;
    #pragma unroll
    for (int nt = 0; nt < 3; ++nt) {
        float s = 0.f, q = 0.f;
        #pragma unroll
        for (int mt = 0; mt < 4; ++mt)
            #pragma unroll
            for (int r = 0; r < 4; ++r) {
                float v = acc[mt][nt][r];
                s += v;
                q = fmaf(v, v, q);
            }
        PS[(wy * 4 + quad) * 96 + wx * 48 + nt * 16 + l16] = s;
        PQ[(wy * 4 + quad) * 96 + wx * 48 + nt * 16 + l16] = q;
    }
    __syncthreads();
    if (tid < 96) {
        float s = 0.f, q = 0.f;
        #pragma unroll
        for (int i = 0; i < 8; ++i) { s += PS[i * 96 + tid]; q += PQ[i * 96 + tid]; }
        psum[mtile * 1536 + n0 + tid] = s;
        psq [mtile * 1536 + n0 + tid] = q;
    }
}

// ---------- generic bf16 MFMA GEMM (proj) ----------
template<bool BIAS, int MT, int NT>
__global__ __launch_bounds__(256) void k_gemm_bf16(const short* __restrict__ A,
                                                   const short* __restrict__ B,
                                                   const float* __restrict__ bias,
                                                   float* __restrict__ C,
                                                   int M, int N, int K) {
    constexpr int BM = MT * 32, BN = NT * 32;
    __shared__ __align__(16) short As[BM * 32];
    __shared__ __align__(16) short Bs[BN * 32];
    const int tid  = threadIdx.x;
    const int lane = tid & 63, wv = tid >> 6;
    const int wy = wv >> 1, wx = wv & 1;
    const int quad = lane >> 4, l16 = lane & 15;
    const int m0 = blockIdx.y * BM, n0 = blockIdx.x * BN;

    f32x4 acc[MT][NT];
    #pragma unroll
    for (int i = 0; i < MT; ++i)
        #pragma unroll
        for (int j = 0; j < NT; ++j)
            #pragma unroll
            for (int r = 0; r < 4; ++r) acc[i][j][r] = 0.f;

    constexpr int LA = 2 * MT, LB = 2 * NT;
    const short* gA[(LA + 3) / 4]; short* lA[(LA + 3) / 4]; int nA = 0;
    #pragma unroll
    for (int L0 = 0; L0 < LA; L0 += 4) {
        int L = L0 + wv;
        if (L < LA) {
            int c = L * 64 + lane;
            gA[nA] = A + (size_t)(m0 + (c >> 2)) * K + (c & 3) * 8;
            lA[nA] = &As[L * 512];
            ++nA;
        }
    }
    const short* gB[(LB + 3) / 4]; short* lB[(LB + 3) / 4]; int nB = 0;
    #pragma unroll
    for (int L0 = 0; L0 < LB; L0 += 4) {
        int L = L0 + wv;
        if (L < LB) {
            int c = L * 64 + lane;
            gB[nB] = B + (size_t)(n0 + (c >> 2)) * K + (c & 3) * 8;
            lB[nB] = &Bs[L * 512];
            ++nB;
        }
    }

    for (int k0 = 0; k0 < K; k0 += 32) {
        __syncthreads();
        for (int i = 0; i < nA; ++i) GLOAD_LDS16(gA[i] + k0, lA[i]);
        for (int i = 0; i < nB; ++i) GLOAD_LDS16(gB[i] + k0, lB[i]);
        __syncthreads();
        short8 aF[MT], bF[NT];
        #pragma unroll
        for (int mt = 0; mt < MT; ++mt)
            aF[mt] = *(const short8*)&As[(wy * MT * 16 + mt * 16 + l16) * 32 + quad * 8];
        #pragma unroll
        for (int nt = 0; nt < NT; ++nt)
            bF[nt] = *(const short8*)&Bs[(wx * NT * 16 + nt * 16 + l16) * 32 + quad * 8];
        #pragma unroll
        for (int mt = 0; mt < MT; ++mt)
            #pragma unroll
            for (int nt = 0; nt < NT; ++nt)
                acc[mt][nt] = __builtin_amdgcn_mfma_f32_16x16x32_bf16(aF[mt], bF[nt], acc[mt][nt], 0, 0, 0);
    }

    float bs[NT];
    #pragma unroll
    for (int nt = 0; nt < NT; ++nt) bs[nt] = BIAS ? bias[n0 + wx * NT * 16 + nt * 16 + l16] : 0.f;
    #pragma unroll
    for (int mt = 0; mt < MT; ++mt)
        #pragma unroll
        for (int r = 0; r < 4; ++r) {
            int row = m0 + wy * MT * 16 + mt * 16 + quad * 4 + r;
            float* Cr = C + (size_t)row * N + n0 + wx * NT * 16 + l16;
            #pragma unroll
            for (int nt = 0; nt < NT; ++nt) Cr[nt * 16] = acc[mt][nt][r] + bs[nt];
        }
}

// ---------- BN finalize + spike + pack to i8 q/k (row-major) and v (transposed) ----------
__global__ __launch_bounds__(256) void k_bn_spike(const short* __restrict__ qkvb,
                           const float* __restrict__ psum, const float* __restrict__ psq,
                           const float* __restrict__ gamma, const float* __restrict__ beta,
                           unsigned char* __restrict__ qp, unsigned char* __restrict__ kp,
                           unsigned char* __restrict__ vt) {
    __shared__ float sa[64], sb[64];
    __shared__ __align__(16) unsigned char tile[64 * 80];
    const int tid = threadIdx.x;
    const int slice = blockIdx.x;            // 0..23
    const int c0 = slice * 64;
    const int r0 = blockIdx.y * 256;
    const int b = r0 >> 10, nb = r0 & 1023;

    if (tid < 64) {
        const int c = c0 + tid;
        double s = 0.0, q = 0.0;
        for (int st = 0; st < 32; ++st) { s += (double)psum[st * 1536 + c]; q += (double)psq[st * 1536 + c]; }
        const double mu  = s / 4096.0;
        const double var = q / 4096.0 - mu * mu;
        const float a = (float)((double)gamma[c] / sqrt(var + 1e-5));
        sa[tid] = a;
        sb[tid] = fmaf(-(float)mu, a, beta[c]);
    }
    __syncthreads();

    const int ch = tid & 63, rq = tid >> 6;
    const float A = sa[ch], Bsh = sb[ch];

    if (slice < 16) {
        const int h = slice & 7;
        unsigned char* base = (slice < 8 ? qp : kp) + (((size_t)b * 8 + h) * 1024 + nb) * 64;
        for (int i = rq; i < 256; i += 4) {
            float v = bf2f((unsigned short)qkvb[(size_t)(r0 + i) * 1536 + c0 + ch]);
            base[(size_t)i * 64 + ch] = (unsigned char)spikef(fmaf(v, A, Bsh));
        }
    } else {
        const int h = slice - 16;
        const int e = tid >> 2, j0 = (tid & 3) * 16;
        unsigned char* vbase = vt + (((size_t)b * 8 + h) * 64 + e) * 1024 + nb;
        for (int rb = 0; rb < 4; ++rb) {
            __syncthreads();
            for (int i = rq; i < 64; i += 4) {
                float v = bf2f((unsigned short)qkvb[(size_t)(r0 + rb * 64 + i) * 1536 + c0 + ch]);
                tile[ch * 80 + i] = (unsigned char)spikef(fmaf(v, A, Bsh));
            }
            __syncthreads();
            *(u32x4*)&vbase[rb * 64 + j0] = *(const u32x4*)&tile[e * 80 + j0];
        }
    }
}

// ---------- fused i8-MFMA attention, 256-wide j-tiles, glds + XOR-swizzled LDS ----------
// Flat grid 512, XCD-swizzled: u = n0tile*32 + bh -> all 16 q-tiles of one (b,h)
// land on one XCD (u%8 = bh%8), so its K/V stays L2-resident on exactly one XCD.
__global__ __launch_bounds__(256) void k_attn(const unsigned char* __restrict__ qp,
                                              const unsigned char* __restrict__ kp,
                                              const unsigned char* __restrict__ vt,
                                              short* __restrict__ sout) {
    __shared__ __align__(16) unsigned char SM[54272];
    unsigned char* Qs = SM;                        // 64 x 64B
    unsigned char* Ks = SM + 4096;                 // 256 x 64B
    unsigned char* Vs = SM + 20480;                // 64 x 256B
    unsigned int* Sb = (unsigned int*)(SM + 36864);// 64 x 68 dw
    const int tid  = threadIdx.x;
    const int lane = tid & 63, w = tid >> 6;
    const int quad = lane >> 4, l16 = lane & 15;
    const int u = blockIdx.x;
    const int bhid = u & 31;                       // XCD = u%8 = bhid%8
    const int b = bhid >> 3, h = bhid & 7;
    const int n0 = (u >> 5) * 64;
    const size_t bh = (size_t)b * 8 + h;

    {
        const int r = tid >> 2, p = tid & 3;
        const int g = p ^ (r & 3) ^ ((r >> 2) & 3);
        GLOAD_LDS16(qp + (bh * 1024 + n0 + r) * 64 + g * 16, Qs + (size_t)tid * 16);
    }
    const unsigned char* gK[4]; unsigned char* lK[4];
    const unsigned char* gV[4]; unsigned char* lV[4];
    #pragma unroll
    for (int i = 0; i < 4; ++i) {
        int c = tid + 256 * i;
        int rk = c >> 2, pk2 = c & 3;
        int gk = pk2 ^ (rk & 3) ^ ((rk >> 2) & 3);
        gK[i] = kp + (bh * 1024 + rk) * 64 + gk * 16;
        lK[i] = Ks + (size_t)c * 16;
        int rv = c >> 4, pv = c & 15;
        int gv = pv ^ (rv & 15);
        gV[i] = vt + (bh * 64 + rv) * 1024 + gv * 16;
        lV[i] = Vs + (size_t)c * 16;
    }
    __syncthreads();
    u32x4 qf[4];
    {
        const int pq = quad ^ (l16 & 3) ^ ((l16 >> 2) & 3);
        #pragma unroll
        for (int mt = 0; mt < 4; ++mt)
            qf[mt] = *(const u32x4*)&Qs[(mt * 16 + l16) * 64 + pq * 16];
    }

    int4v of[4];
    #pragma unroll
    for (int mt = 0; mt < 4; ++mt)
        #pragma unroll
        for (int r = 0; r < 4; ++r) of[mt][r] = 0;

    const int pk = quad ^ (l16 & 3) ^ ((l16 >> 2) & 3);

    for (int j0 = 0; j0 < 1024; j0 += 256) {
        __syncthreads();
        #pragma unroll
        for (int i = 0; i < 4; ++i) {
            GLOAD_LDS16(gK[i] + (size_t)j0 * 64, lK[i]);
            GLOAD_LDS16(gV[i] + j0, lV[i]);
        }
        __syncthreads();

        #pragma unroll
        for (int jt = 0; jt < 4; ++jt) {
            u32x4 kf = *(const u32x4*)&Ks[(w * 64 + jt * 16 + l16) * 64 + pk * 16];
            #pragma unroll
            for (int mt = 0; mt < 4; ++mt) {
                int4v z;
                #pragma unroll
                for (int r = 0; r < 4; ++r) z[r] = 0;
                int4v s = mfma_i8(kf, qf[mt], z);
                unsigned int pkk = 0;
                #pragma unroll
                for (int r = 0; r < 4; ++r) {
                    int v = s[r]; v = v < 0 ? 0 : (v > 4 ? 4 : v);
                    pkk |= (unsigned int)v << (8 * r);
                }
                Sb[(mt * 16 + l16) * 68 + w * 16 + jt * 4 + quad] = pkk;
            }
        }
        __syncthreads();

        #pragma unroll
        for (int kk = 0; kk < 4; ++kk) {
            const int pv = (kk * 4 + quad) ^ l16;
            u32x4 bV = *(const u32x4*)&Vs[(w * 16 + l16) * 256 + pv * 16];
            #pragma unroll
            for (int mt = 0; mt < 4; ++mt) {
                u32x4 aS = *(const u32x4*)&Sb[(mt * 16 + l16) * 68 + kk * 16 + quad * 4];
                of[mt] = mfma_i8(aS, bV, of[mt]);
            }
        }
    }

    #pragma unroll
    for (int mt = 0; mt < 4; ++mt)
        #pragma unroll
        for (int r = 0; r < 4; ++r) {
            size_t orow = (size_t)b * 1024 + n0 + mt * 16 + quad * 4 + r;
            sout[orow * 512 + h * 64 + w * 16 + l16] =
                (short)f2bf(spikef((float)of[mt][r] * 0.125f));
        }
}

extern "C" void kernel_launch(void* const* d_in, const int* in_sizes, int n_in,
                              void* d_out, int out_size, void* d_ws, size_t ws_size,
                              hipStream_t stream) {
    const float* x     = (const float*)d_in[0];
    const float* Wqkv  = (const float*)d_in[1];
    const float* gamma = (const float*)d_in[2];
    const float* beta  = (const float*)d_in[3];
    const float* Wproj = (const float*)d_in[4];
    const float* bproj = (const float*)d_in[5];
    float* out = (float*)d_out;

    char* w = (char*)d_ws;
    short* xs            = (short*)(w);                     // 4 MB; reused as sout
    short* Wqkv2         = (short*)(w + 8388608);           // 1.5 MB (hi only)
    short* Wproj2        = (short*)(w + 11534336);          // 0.5 MB
    short* qkvb          = (short*)(w + 12582912);          // 12 MB (bf16)
    unsigned char* qp    = (unsigned char*)(w + 37748736);  // 2 MB
    unsigned char* kp    = (unsigned char*)(w + 41943040);  // 2 MB
    unsigned char* vt    = (unsigned char*)(w + 46137344);  // 2 MB
    float* psum          = (float*)(w + 50331648);
    float* psq           = psum + 32 * 1536;
    short* sout          = xs;                              // xs dead after qkv GEMM

    k_prep<<<3072, 256, 0, stream>>>(x, Wqkv, Wproj, xs, Wqkv2, Wproj2);
    k_gemm_qkv<<<512, 256, 0, stream>>>(xs, Wqkv2, qkvb, psum, psq);
    k_bn_spike<<<dim3(24, 16), 256, 0, stream>>>(qkvb, psum, psq, gamma, beta, qp, kp, vt);
    k_attn<<<512, 256, 0, stream>>>(qp, kp, vt, sout);
    k_gemm_bf16<true, 1, 4><<<dim3(4, 128), 256, 0, stream>>>(
        sout, Wproj2, bproj, out, 4096, 512, 512);
}

// Round 15
// 113.313 us; speedup vs baseline: 2.8329x; 1.0242x over previous
//
#include <hip/hip_runtime.h>

typedef __attribute__((ext_vector_type(8))) short short8;
typedef __attribute__((ext_vector_type(4))) short short4v;
typedef __attribute__((ext_vector_type(8))) signed char s8x8;
typedef __attribute__((ext_vector_type(4))) unsigned char u8x4;
typedef __attribute__((ext_vector_type(4))) float f32x4;
typedef __attribute__((ext_vector_type(4))) int int4v;
typedef __attribute__((ext_vector_type(4))) unsigned int u32x4;

#define THRE 4.0f

#define GLOAD_LDS16(g, l) \
    __builtin_amdgcn_global_load_lds((const __attribute__((address_space(1))) void*)(g), \
                                     (__attribute__((address_space(3))) void*)(l), 16, 0, 0)

__device__ __forceinline__ float spikef(float x) {
    return floorf(fminf(fmaxf(x, 0.0f), THRE) + 0.5f);
}
__device__ __forceinline__ unsigned short f2bf(float f) {   // truncate; exact for small ints
    return (unsigned short)(__builtin_bit_cast(unsigned int, f) >> 16);
}
__device__ __forceinline__ unsigned short f2bf_rn(float f) { // round-to-nearest
    unsigned u = __builtin_bit_cast(unsigned int, f);
    unsigned r = ((u >> 16) & 1u) + 0x7FFFu;
    return (unsigned short)((u + r) >> 16);
}
__device__ __forceinline__ float bf2f(unsigned short s) {
    return __builtin_bit_cast(float, (unsigned int)s << 16);
}
__device__ __forceinline__ int4v mfma_i8(u32x4 a, u32x4 b, int4v c) {
    return __builtin_amdgcn_mfma_i32_16x16x64_i8(__builtin_bit_cast(int4v, a),
                                                 __builtin_bit_cast(int4v, b), c, 0, 0, 0);
}

// ---------- prep: x -> i8 spike; Wqkv -> i8 per-row quant + scale; Wproj -> bf16 hi ----------
// grid 2688: [0,2048) x-spike; [2048,2432) Wqkv rows (4 rows/block, 1 wave each); rest Wproj.
__global__ void k_prep(const float* __restrict__ x,
                       const float* __restrict__ Wq, const float* __restrict__ Wp,
                       unsigned char* __restrict__ xs8, signed char* __restrict__ Wq8,
                       float* __restrict__ wscale, short* __restrict__ Wpd) {
    const int blk = blockIdx.x, tid = threadIdx.x;
    if (blk < 2048) {                                    // x: 2097152 floats, 4/thread
        const int i = blk * 256 + tid;
        const float4 v = *(const float4*)&x[(size_t)i * 4];
        u8x4 o;
        o.x = (unsigned char)spikef(v.x);
        o.y = (unsigned char)spikef(v.y);
        o.z = (unsigned char)spikef(v.z);
        o.w = (unsigned char)spikef(v.w);
        *(u8x4*)&xs8[(size_t)i * 4] = o;
    } else if (blk < 2432) {                             // Wqkv: 1536 rows of 512
        const int row = (blk - 2048) * 4 + (tid >> 6);
        const int lane = tid & 63;
        const float* wr = Wq + (size_t)row * 512 + lane * 8;
        float w[8];
        float mx = 0.f;
        #pragma unroll
        for (int i = 0; i < 8; ++i) { w[i] = wr[i]; mx = fmaxf(mx, fabsf(w[i])); }
        #pragma unroll
        for (int o = 32; o > 0; o >>= 1) mx = fmaxf(mx, __shfl_xor(mx, o, 64));
        const float inv = mx > 0.f ? 127.0f / mx : 0.f;
        s8x8 q;
        #pragma unroll
        for (int i = 0; i < 8; ++i) q[i] = (signed char)rintf(w[i] * inv);
        *(s8x8*)&Wq8[(size_t)row * 512 + lane * 8] = q;
        if (lane == 0) wscale[row] = mx > 0.f ? mx / 127.0f : 0.f;
    } else {                                             // Wproj: 262144 floats, 4/thread
        const int i = (blk - 2432) * 256 + tid;
        const float4 v = *(const float4*)&Wp[(size_t)i * 4];
        short4v o;
        o.x = (short)(__builtin_bit_cast(unsigned int, v.x) >> 16);
        o.y = (short)(__builtin_bit_cast(unsigned int, v.y) >> 16);
        o.z = (short)(__builtin_bit_cast(unsigned int, v.z) >> 16);
        o.w = (short)(__builtin_bit_cast(unsigned int, v.w) >> 16);
        *(short4v*)&Wpd[(size_t)i * 4] = o;
    }
}

// ---------- qkv GEMM (i8): M=4096 N=1536 K=512, BM=128 BN=96 BK=128B; bf16 out ----------
// A = xs8 {0..4} exact; B = per-row-quantized Wqkv; i32 accumulate (exact); epilogue * wscale.
// Flat grid 512, XCD-swizzled (u%8 = mtile%8). XOR-swizzled LDS (rows 8 chunks, ^(r&7)).
__global__ __launch_bounds__(256) void k_gemm_qkv(const unsigned char* __restrict__ A,
                                                  const signed char* __restrict__ B,
                                                  const float* __restrict__ wscale,
                                                  short* __restrict__ C,
                                                  float* __restrict__ psum,
                                                  float* __restrict__ psq) {
    __shared__ __align__(16) unsigned char As[128 * 128];  // 16 KB
    __shared__ __align__(16) unsigned char Bs[96 * 128];   // 12 KB
    const int tid  = threadIdx.x;
    const int lane = tid & 63, wv = tid >> 6;
    const int wy = wv >> 1, wx = wv & 1;
    const int quad = lane >> 4, l16 = lane & 15;
    const int u = blockIdx.x;
    const int mtile = u & 31;                      // XCD = u%8
    const int m0 = mtile * 128, n0 = (u >> 5) * 96;
    const int N = 1536;

    int4v acc[4][3];
    #pragma unroll
    for (int i = 0; i < 4; ++i)
        #pragma unroll
        for (int j = 0; j < 3; ++j)
            #pragma unroll
            for (int r = 0; r < 4; ++r) acc[i][j][r] = 0;

    const unsigned char* gA[4]; unsigned char* lA[4];
    #pragma unroll
    for (int i = 0; i < 4; ++i) {
        int L = wv + 4 * i;                        // 16 wave-loads, rows L*8..L*8+7
        int c = L * 64 + lane;
        int r = c >> 3, g = (c & 7) ^ (r & 7);
        gA[i] = A + (size_t)(m0 + r) * 512 + g * 16;
        lA[i] = &As[(size_t)c * 16];
    }
    const unsigned char* gB[3]; unsigned char* lB[3];
    #pragma unroll
    for (int i = 0; i < 3; ++i) {
        int L = wv + 4 * i;                        // 12 wave-loads, rows 0..95
        int c = L * 64 + lane;
        int r = c >> 3, g = (c & 7) ^ (r & 7);
        gB[i] = (const unsigned char*)B + (size_t)(n0 + r) * 512 + g * 16;
        lB[i] = &Bs[(size_t)c * 16];
    }

    for (int k0 = 0; k0 < 512; k0 += 128) {
        __syncthreads();
        #pragma unroll
        for (int i = 0; i < 4; ++i) GLOAD_LDS16(gA[i] + k0, lA[i]);
        #pragma unroll
        for (int i = 0; i < 3; ++i) GLOAD_LDS16(gB[i] + k0, lB[i]);
        __syncthreads();
        #pragma unroll
        for (int kk = 0; kk < 2; ++kk) {
            u32x4 aF[4], bF[3];
            #pragma unroll
            for (int mt = 0; mt < 4; ++mt) {
                const int r = wy * 64 + mt * 16 + l16;
                aF[mt] = *(const u32x4*)&As[(size_t)r * 128 + (((kk * 4 + quad) ^ (r & 7)) * 16)];
            }
            #pragma unroll
            for (int nt = 0; nt < 3; ++nt) {
                const int r = wx * 48 + nt * 16 + l16;
                bF[nt] = *(const u32x4*)&Bs[(size_t)r * 128 + (((kk * 4 + quad) ^ (r & 7)) * 16)];
            }
            #pragma unroll
            for (int mt = 0; mt < 4; ++mt)
                #pragma unroll
                for (int nt = 0; nt < 3; ++nt)
                    acc[mt][nt] = mfma_i8(aF[mt], bF[nt], acc[mt][nt]);
        }
    }

    float sc[3];
    #pragma unroll
    for (int nt = 0; nt < 3; ++nt) sc[nt] = wscale[n0 + wx * 48 + nt * 16 + l16];

    float vacc[4][3][4];
    #pragma unroll
    for (int mt = 0; mt < 4; ++mt)
        #pragma unroll
        for (int r = 0; r < 4; ++r) {
            int row = m0 + wy * 64 + mt * 16 + quad * 4 + r;
            short* Cr = C + (size_t)row * N + n0 + wx * 48 + l16;
            #pragma unroll
            for (int nt = 0; nt < 3; ++nt) {
                float v = (float)acc[mt][nt][r] * sc[nt];
                vacc[mt][nt][r] = v;
                Cr[nt * 16] = (short)f2bf_rn(v);
            }
        }

    __syncthreads();
    float* PS = (float*)As;   // [8][96]
    float* PQ = (float*)Bs;
    #pragma unroll
    for (int nt = 0; nt < 3; ++nt) {
        float s = 0.f, q = 0.f;
        #pragma unroll
        for (int mt = 0; mt < 4; ++mt)
            #pragma unroll
            for (int r = 0; r < 4; ++r) {
                float v = vacc[mt][nt][r];
                s += v;
                q = fmaf(v, v, q);
            }
        PS[(wy * 4 + quad) * 96 + wx * 48 + nt * 16 + l16] = s;
        PQ[(wy * 4 + quad) * 96 + wx * 48 + nt * 16 + l16] = q;
    }
    __syncthreads();
    if (tid < 96) {
        float s = 0.f, q = 0.f;
        #pragma unroll
        for (int i = 0; i < 8; ++i) { s += PS[i * 96 + tid]; q += PQ[i * 96 + tid]; }
        psum[mtile * 1536 + n0 + tid] = s;
        psq [mtile * 1536 + n0 + tid] = q;
    }
}

// ---------- generic bf16 MFMA GEMM (proj) ----------
template<bool BIAS, int MT, int NT>
__global__ __launch_bounds__(256) void k_gemm_bf16(const short* __restrict__ A,
                                                   const short* __restrict__ B,
                                                   const float* __restrict__ bias,
                                                   float* __restrict__ C,
                                                   int M, int N, int K) {
    constexpr int BM = MT * 32, BN = NT * 32;
    __shared__ __align__(16) short As[BM * 32];
    __shared__ __align__(16) short Bs[BN * 32];
    const int tid  = threadIdx.x;
    const int lane = tid & 63, wv = tid >> 6;
    const int wy = wv >> 1, wx = wv & 1;
    const int quad = lane >> 4, l16 = lane & 15;
    const int m0 = blockIdx.y * BM, n0 = blockIdx.x * BN;

    f32x4 acc[MT][NT];
    #pragma unroll
    for (int i = 0; i < MT; ++i)
        #pragma unroll
        for (int j = 0; j < NT; ++j)
            #pragma unroll
            for (int r = 0; r < 4; ++r) acc[i][j][r] = 0.f;

    constexpr int LA = 2 * MT, LB = 2 * NT;
    const short* gA[(LA + 3) / 4]; short* lA[(LA + 3) / 4]; int nA = 0;
    #pragma unroll
    for (int L0 = 0; L0 < LA; L0 += 4) {
        int L = L0 + wv;
        if (L < LA) {
            int c = L * 64 + lane;
            gA[nA] = A + (size_t)(m0 + (c >> 2)) * K + (c & 3) * 8;
            lA[nA] = &As[L * 512];
            ++nA;
        }
    }
    const short* gB[(LB + 3) / 4]; short* lB[(LB + 3) / 4]; int nB = 0;
    #pragma unroll
    for (int L0 = 0; L0 < LB; L0 += 4) {
        int L = L0 + wv;
        if (L < LB) {
            int c = L * 64 + lane;
            gB[nB] = B + (size_t)(n0 + (c >> 2)) * K + (c & 3) * 8;
            lB[nB] = &Bs[L * 512];
            ++nB;
        }
    }

    for (int k0 = 0; k0 < K; k0 += 32) {
        __syncthreads();
        for (int i = 0; i < nA; ++i) GLOAD_LDS16(gA[i] + k0, lA[i]);
        for (int i = 0; i < nB; ++i) GLOAD_LDS16(gB[i] + k0, lB[i]);
        __syncthreads();
        short8 aF[MT], bF[NT];
        #pragma unroll
        for (int mt = 0; mt < MT; ++mt)
            aF[mt] = *(const short8*)&As[(wy * MT * 16 + mt * 16 + l16) * 32 + quad * 8];
        #pragma unroll
        for (int nt = 0; nt < NT; ++nt)
            bF[nt] = *(const short8*)&Bs[(wx * NT * 16 + nt * 16 + l16) * 32 + quad * 8];
        #pragma unroll
        for (int mt = 0; mt < MT; ++mt)
            #pragma unroll
            for (int nt = 0; nt < NT; ++nt)
                acc[mt][nt] = __builtin_amdgcn_mfma_f32_16x16x32_bf16(aF[mt], bF[nt], acc[mt][nt], 0, 0, 0);
    }

    float bs[NT];
    #pragma unroll
    for (int nt = 0; nt < NT; ++nt) bs[nt] = BIAS ? bias[n0 + wx * NT * 16 + nt * 16 + l16] : 0.f;
    #pragma unroll
    for (int mt = 0; mt < MT; ++mt)
        #pragma unroll
        for (int r = 0; r < 4; ++r) {
            int row = m0 + wy * MT * 16 + mt * 16 + quad * 4 + r;
            float* Cr = C + (size_t)row * N + n0 + wx * NT * 16 + l16;
            #pragma unroll
            for (int nt = 0; nt < NT; ++nt) Cr[nt * 16] = acc[mt][nt][r] + bs[nt];
        }
}

// ---------- BN finalize + spike + pack to i8 q/k (row-major) and v (transposed) ----------
__global__ __launch_bounds__(256) void k_bn_spike(const short* __restrict__ qkvb,
                           const float* __restrict__ psum, const float* __restrict__ psq,
                           const float* __restrict__ gamma, const float* __restrict__ beta,
                           unsigned char* __restrict__ qp, unsigned char* __restrict__ kp,
                           unsigned char* __restrict__ vt) {
    __shared__ float sa[64], sb[64];
    __shared__ __align__(16) unsigned char tile[64 * 80];
    const int tid = threadIdx.x;
    const int slice = blockIdx.x;            // 0..23
    const int c0 = slice * 64;
    const int r0 = blockIdx.y * 256;
    const int b = r0 >> 10, nb = r0 & 1023;

    if (tid < 64) {
        const int c = c0 + tid;
        double s = 0.0, q = 0.0;
        for (int st = 0; st < 32; ++st) { s += (double)psum[st * 1536 + c]; q += (double)psq[st * 1536 + c]; }
        const double mu  = s / 4096.0;
        const double var = q / 4096.0 - mu * mu;
        const float a = (float)((double)gamma[c] / sqrt(var + 1e-5));
        sa[tid] = a;
        sb[tid] = fmaf(-(float)mu, a, beta[c]);
    }
    __syncthreads();

    const int ch = tid & 63, rq = tid >> 6;
    const float A = sa[ch], Bsh = sb[ch];

    if (slice < 16) {
        const int h = slice & 7;
        unsigned char* base = (slice < 8 ? qp : kp) + (((size_t)b * 8 + h) * 1024 + nb) * 64;
        for (int i = rq; i < 256; i += 4) {
            float v = bf2f((unsigned short)qkvb[(size_t)(r0 + i) * 1536 + c0 + ch]);
            base[(size_t)i * 64 + ch] = (unsigned char)spikef(fmaf(v, A, Bsh));
        }
    } else {
        const int h = slice - 16;
        const int e = tid >> 2, j0 = (tid & 3) * 16;
        unsigned char* vbase = vt + (((size_t)b * 8 + h) * 64 + e) * 1024 + nb;
        for (int rb = 0; rb < 4; ++rb) {
            __syncthreads();
            for (int i = rq; i < 64; i += 4) {
                float v = bf2f((unsigned short)qkvb[(size_t)(r0 + rb * 64 + i) * 1536 + c0 + ch]);
                tile[ch * 80 + i] = (unsigned char)spikef(fmaf(v, A, Bsh));
            }
            __syncthreads();
            *(u32x4*)&vbase[rb * 64 + j0] = *(const u32x4*)&tile[e * 80 + j0];
        }
    }
}

// ---------- fused i8-MFMA attention, 256-wide j-tiles, glds + XOR-swizzled LDS ----------
// Flat grid 512, XCD-swizzled: u = n0tile*32 + bh (u%8 = bh%8 -> K/V L2-resident per XCD).
__global__ __launch_bounds__(256) void k_attn(const unsigned char* __restrict__ qp,
                                              const unsigned char* __restrict__ kp,
                                              const unsigned char* __restrict__ vt,
                                              short* __restrict__ sout) {
    __shared__ __align__(16) unsigned char SM[54272];
    unsigned char* Qs = SM;                        // 64 x 64B
    unsigned char* Ks = SM + 4096;                 // 256 x 64B
    unsigned char* Vs = SM + 20480;                // 64 x 256B
    unsigned int* Sb = (unsigned int*)(SM + 36864);// 64 x 68 dw
    const int tid  = threadIdx.x;
    const int lane = tid & 63, w = tid >> 6;
    const int quad = lane >> 4, l16 = lane & 15;
    const int u = blockIdx.x;
    const int bhid = u & 31;                       // XCD = u%8 = bhid%8
    const int b = bhid >> 3, h = bhid & 7;
    const int n0 = (u >> 5) * 64;
    const size_t bh = (size_t)b * 8 + h;

    {
        const int r = tid >> 2, p = tid & 3;
        const int g = p ^ (r & 3) ^ ((r >> 2) & 3);
        GLOAD_LDS16(qp + (bh * 1024 + n0 + r) * 64 + g * 16, Qs + (size_t)tid * 16);
    }
    const unsigned char* gK[4]; unsigned char* lK[4];
    const unsigned char* gV[4]; unsigned char* lV[4];
    #pragma unroll
    for (int i = 0; i < 4; ++i) {
        int c = tid + 256 * i;
        int rk = c >> 2, pk2 = c & 3;
        int gk = pk2 ^ (rk & 3) ^ ((rk >> 2) & 3);
        gK[i] = kp + (bh * 1024 + rk) * 64 + gk * 16;
        lK[i] = Ks + (size_t)c * 16;
        int rv = c >> 4, pv = c & 15;
        int gv = pv ^ (rv & 15);
        gV[i] = vt + (bh * 64 + rv) * 1024 + gv * 16;
        lV[i] = Vs + (size_t)c * 16;
    }
    __syncthreads();
    u32x4 qf[4];
    {
        const int pq = quad ^ (l16 & 3) ^ ((l16 >> 2) & 3);
        #pragma unroll
        for (int mt = 0; mt < 4; ++mt)
            qf[mt] = *(const u32x4*)&Qs[(mt * 16 + l16) * 64 + pq * 16];
    }

    int4v of[4];
    #pragma unroll
    for (int mt = 0; mt < 4; ++mt)
        #pragma unroll
        for (int r = 0; r < 4; ++r) of[mt][r] = 0;

    const int pk = quad ^ (l16 & 3) ^ ((l16 >> 2) & 3);

    for (int j0 = 0; j0 < 1024; j0 += 256) {
        __syncthreads();
        #pragma unroll
        for (int i = 0; i < 4; ++i) {
            GLOAD_LDS16(gK[i] + (size_t)j0 * 64, lK[i]);
            GLOAD_LDS16(gV[i] + j0, lV[i]);
        }
        __syncthreads();

        #pragma unroll
        for (int jt = 0; jt < 4; ++jt) {
            u32x4 kf = *(const u32x4*)&Ks[(w * 64 + jt * 16 + l16) * 64 + pk * 16];
            #pragma unroll
            for (int mt = 0; mt < 4; ++mt) {
                int4v z;
                #pragma unroll
                for (int r = 0; r < 4; ++r) z[r] = 0;
                int4v s = mfma_i8(kf, qf[mt], z);
                unsigned int pkk = 0;
                #pragma unroll
                for (int r = 0; r < 4; ++r) {
                    int v = s[r]; v = v < 0 ? 0 : (v > 4 ? 4 : v);
                    pkk |= (unsigned int)v << (8 * r);
                }
                Sb[(mt * 16 + l16) * 68 + w * 16 + jt * 4 + quad] = pkk;
            }
        }
        __syncthreads();

        #pragma unroll
        for (int kk = 0; kk < 4; ++kk) {
            const int pv = (kk * 4 + quad) ^ l16;
            u32x4 bV = *(const u32x4*)&Vs[(w * 16 + l16) * 256 + pv * 16];
            #pragma unroll
            for (int mt = 0; mt < 4; ++mt) {
                u32x4 aS = *(const u32x4*)&Sb[(mt * 16 + l16) * 68 + kk * 16 + quad * 4];
                of[mt] = mfma_i8(aS, bV, of[mt]);
            }
        }
    }

    #pragma unroll
    for (int mt = 0; mt < 4; ++mt)
        #pragma unroll
        for (int r = 0; r < 4; ++r) {
            size_t orow = (size_t)b * 1024 + n0 + mt * 16 + quad * 4 + r;
            sout[orow * 512 + h * 64 + w * 16 + l16] =
                (short)f2bf(spikef((float)of[mt][r] * 0.125f));
        }
}

extern "C" void kernel_launch(void* const* d_in, const int* in_sizes, int n_in,
                              void* d_out, int out_size, void* d_ws, size_t ws_size,
                              hipStream_t stream) {
    const float* x     = (const float*)d_in[0];
    const float* Wqkv  = (const float*)d_in[1];
    const float* gamma = (const float*)d_in[2];
    const float* beta  = (const float*)d_in[3];
    const float* Wproj = (const float*)d_in[4];
    const float* bproj = (const float*)d_in[5];
    float* out = (float*)d_out;

    char* w = (char*)d_ws;
    unsigned char* xs8   = (unsigned char*)(w);             // 2 MB; region reused as sout (4 MB)
    signed char* Wq8     = (signed char*)(w + 8388608);     // 0.75 MB
    float* wscale        = (float*)(w + 9437184);           // 6 KB
    short* Wproj2        = (short*)(w + 11534336);          // 0.5 MB
    short* qkvb          = (short*)(w + 12582912);          // 12 MB (bf16)
    unsigned char* qp    = (unsigned char*)(w + 37748736);  // 2 MB
    unsigned char* kp    = (unsigned char*)(w + 41943040);  // 2 MB
    unsigned char* vt    = (unsigned char*)(w + 46137344);  // 2 MB
    float* psum          = (float*)(w + 50331648);
    float* psq           = psum + 32 * 1536;
    short* sout          = (short*)(w);                     // xs8 dead after qkv GEMM

    k_prep<<<2688, 256, 0, stream>>>(x, Wqkv, Wproj, xs8, Wq8, wscale, Wproj2);
    k_gemm_qkv<<<512, 256, 0, stream>>>(xs8, Wq8, wscale, qkvb, psum, psq);
    k_bn_spike<<<dim3(24, 16), 256, 0, stream>>>(qkvb, psum, psq, gamma, beta, qp, kp, vt);
    k_attn<<<512, 256, 0, stream>>>(qp, kp, vt, sout);
    k_gemm_bf16<true, 1, 4><<<dim3(4, 128), 256, 0, stream>>>(
        sout, Wproj2, bproj, out, 4096, 512, 512);
}

// Round 16
// 110.171 us; speedup vs baseline: 2.9137x; 1.0285x over previous
//
#include <hip/hip_runtime.h>

typedef __attribute__((ext_vector_type(8))) short short8;
typedef __attribute__((ext_vector_type(4))) short short4v;
typedef __attribute__((ext_vector_type(8))) signed char s8x8;
typedef __attribute__((ext_vector_type(4))) unsigned char u8x4;
typedef __attribute__((ext_vector_type(4))) float f32x4;
typedef __attribute__((ext_vector_type(4))) int int4v;
typedef __attribute__((ext_vector_type(4))) unsigned int u32x4;

#define THRE 4.0f

#define GLOAD_LDS16(g, l) \
    __builtin_amdgcn_global_load_lds((const __attribute__((address_space(1))) void*)(g), \
                                     (__attribute__((address_space(3))) void*)(l), 16, 0, 0)

__device__ __forceinline__ float spikef(float x) {
    return floorf(fminf(fmaxf(x, 0.0f), THRE) + 0.5f);
}
__device__ __forceinline__ unsigned short f2bf(float f) {   // truncate; exact for small ints
    return (unsigned short)(__builtin_bit_cast(unsigned int, f) >> 16);
}
__device__ __forceinline__ unsigned short f2bf_rn(float f) { // round-to-nearest
    unsigned u = __builtin_bit_cast(unsigned int, f);
    unsigned r = ((u >> 16) & 1u) + 0x7FFFu;
    return (unsigned short)((u + r) >> 16);
}
__device__ __forceinline__ float bf2f(unsigned short s) {
    return __builtin_bit_cast(float, (unsigned int)s << 16);
}
__device__ __forceinline__ int4v mfma_i8(u32x4 a, u32x4 b, int4v c) {
    return __builtin_amdgcn_mfma_i32_16x16x64_i8(__builtin_bit_cast(int4v, a),
                                                 __builtin_bit_cast(int4v, b), c, 0, 0, 0);
}

// ---------- prep: x -> i8 spike; Wqkv -> i8 per-row quant + scale; Wproj -> bf16 hi ----------
__global__ void k_prep(const float* __restrict__ x,
                       const float* __restrict__ Wq, const float* __restrict__ Wp,
                       unsigned char* __restrict__ xs8, signed char* __restrict__ Wq8,
                       float* __restrict__ wscale, short* __restrict__ Wpd) {
    const int blk = blockIdx.x, tid = threadIdx.x;
    if (blk < 2048) {                                    // x: 2097152 floats, 4/thread
        const int i = blk * 256 + tid;
        const float4 v = *(const float4*)&x[(size_t)i * 4];
        u8x4 o;
        o.x = (unsigned char)spikef(v.x);
        o.y = (unsigned char)spikef(v.y);
        o.z = (unsigned char)spikef(v.z);
        o.w = (unsigned char)spikef(v.w);
        *(u8x4*)&xs8[(size_t)i * 4] = o;
    } else if (blk < 2432) {                             // Wqkv: 1536 rows of 512
        const int row = (blk - 2048) * 4 + (tid >> 6);
        const int lane = tid & 63;
        const float* wr = Wq + (size_t)row * 512 + lane * 8;
        float w[8];
        float mx = 0.f;
        #pragma unroll
        for (int i = 0; i < 8; ++i) { w[i] = wr[i]; mx = fmaxf(mx, fabsf(w[i])); }
        #pragma unroll
        for (int o = 32; o > 0; o >>= 1) mx = fmaxf(mx, __shfl_xor(mx, o, 64));
        const float inv = mx > 0.f ? 127.0f / mx : 0.f;
        s8x8 q;
        #pragma unroll
        for (int i = 0; i < 8; ++i) q[i] = (signed char)rintf(w[i] * inv);
        *(s8x8*)&Wq8[(size_t)row * 512 + lane * 8] = q;
        if (lane == 0) wscale[row] = mx > 0.f ? mx / 127.0f : 0.f;
    } else {                                             // Wproj: 262144 floats, 4/thread
        const int i = (blk - 2432) * 256 + tid;
        const float4 v = *(const float4*)&Wp[(size_t)i * 4];
        short4v o;
        o.x = (short)(__builtin_bit_cast(unsigned int, v.x) >> 16);
        o.y = (short)(__builtin_bit_cast(unsigned int, v.y) >> 16);
        o.z = (short)(__builtin_bit_cast(unsigned int, v.z) >> 16);
        o.w = (short)(__builtin_bit_cast(unsigned int, v.w) >> 16);
        *(short4v*)&Wpd[(size_t)i * 4] = o;
    }
}

// ---------- qkv GEMM (i8): M=4096 N=1536 K=512, BM=128 BN=96 BK=128B; bf16 out ----------
__global__ __launch_bounds__(256) void k_gemm_qkv(const unsigned char* __restrict__ A,
                                                  const signed char* __restrict__ B,
                                                  const float* __restrict__ wscale,
                                                  short* __restrict__ C,
                                                  float* __restrict__ psum,
                                                  float* __restrict__ psq) {
    __shared__ __align__(16) unsigned char As[128 * 128];  // 16 KB
    __shared__ __align__(16) unsigned char Bs[96 * 128];   // 12 KB
    const int tid  = threadIdx.x;
    const int lane = tid & 63, wv = tid >> 6;
    const int wy = wv >> 1, wx = wv & 1;
    const int quad = lane >> 4, l16 = lane & 15;
    const int u = blockIdx.x;
    const int mtile = u & 31;                      // XCD = u%8
    const int m0 = mtile * 128, n0 = (u >> 5) * 96;
    const int N = 1536;

    int4v acc[4][3];
    #pragma unroll
    for (int i = 0; i < 4; ++i)
        #pragma unroll
        for (int j = 0; j < 3; ++j)
            #pragma unroll
            for (int r = 0; r < 4; ++r) acc[i][j][r] = 0;

    const unsigned char* gA[4]; unsigned char* lA[4];
    #pragma unroll
    for (int i = 0; i < 4; ++i) {
        int L = wv + 4 * i;
        int c = L * 64 + lane;
        int r = c >> 3, g = (c & 7) ^ (r & 7);
        gA[i] = A + (size_t)(m0 + r) * 512 + g * 16;
        lA[i] = &As[(size_t)c * 16];
    }
    const unsigned char* gB[3]; unsigned char* lB[3];
    #pragma unroll
    for (int i = 0; i < 3; ++i) {
        int L = wv + 4 * i;
        int c = L * 64 + lane;
        int r = c >> 3, g = (c & 7) ^ (r & 7);
        gB[i] = (const unsigned char*)B + (size_t)(n0 + r) * 512 + g * 16;
        lB[i] = &Bs[(size_t)c * 16];
    }

    for (int k0 = 0; k0 < 512; k0 += 128) {
        __syncthreads();
        #pragma unroll
        for (int i = 0; i < 4; ++i) GLOAD_LDS16(gA[i] + k0, lA[i]);
        #pragma unroll
        for (int i = 0; i < 3; ++i) GLOAD_LDS16(gB[i] + k0, lB[i]);
        __syncthreads();
        #pragma unroll
        for (int kk = 0; kk < 2; ++kk) {
            u32x4 aF[4], bF[3];
            #pragma unroll
            for (int mt = 0; mt < 4; ++mt) {
                const int r = wy * 64 + mt * 16 + l16;
                aF[mt] = *(const u32x4*)&As[(size_t)r * 128 + (((kk * 4 + quad) ^ (r & 7)) * 16)];
            }
            #pragma unroll
            for (int nt = 0; nt < 3; ++nt) {
                const int r = wx * 48 + nt * 16 + l16;
                bF[nt] = *(const u32x4*)&Bs[(size_t)r * 128 + (((kk * 4 + quad) ^ (r & 7)) * 16)];
            }
            #pragma unroll
            for (int mt = 0; mt < 4; ++mt)
                #pragma unroll
                for (int nt = 0; nt < 3; ++nt)
                    acc[mt][nt] = mfma_i8(aF[mt], bF[nt], acc[mt][nt]);
        }
    }

    float sc[3];
    #pragma unroll
    for (int nt = 0; nt < 3; ++nt) sc[nt] = wscale[n0 + wx * 48 + nt * 16 + l16];

    float vacc[4][3][4];
    #pragma unroll
    for (int mt = 0; mt < 4; ++mt)
        #pragma unroll
        for (int r = 0; r < 4; ++r) {
            int row = m0 + wy * 64 + mt * 16 + quad * 4 + r;
            short* Cr = C + (size_t)row * N + n0 + wx * 48 + l16;
            #pragma unroll
            for (int nt = 0; nt < 3; ++nt) {
                float v = (float)acc[mt][nt][r] * sc[nt];
                vacc[mt][nt][r] = v;
                Cr[nt * 16] = (short)f2bf_rn(v);
            }
        }

    __syncthreads();
    float* PS = (float*)As;   // [8][96]
    float* PQ = (float*)Bs;
    #pragma unroll
    for (int nt = 0; nt < 3; ++nt) {
        float s = 0.f, q = 0.f;
        #pragma unroll
        for (int mt = 0; mt < 4; ++mt)
            #pragma unroll
            for (int r = 0; r < 4; ++r) {
                float v = vacc[mt][nt][r];
                s += v;
                q = fmaf(v, v, q);
            }
        PS[(wy * 4 + quad) * 96 + wx * 48 + nt * 16 + l16] = s;
        PQ[(wy * 4 + quad) * 96 + wx * 48 + nt * 16 + l16] = q;
    }
    __syncthreads();
    if (tid < 96) {
        float s = 0.f, q = 0.f;
        #pragma unroll
        for (int i = 0; i < 8; ++i) { s += PS[i * 96 + tid]; q += PQ[i * 96 + tid]; }
        psum[mtile * 1536 + n0 + tid] = s;
        psq [mtile * 1536 + n0 + tid] = q;
    }
}

// ---------- proj GEMM (bf16): M=4096 N=512 K=512, BM=32 BN=128 BK=64, XOR swizzle ----------
// Flat grid 512, XCD-swizzled (u%8 = mtile%8). Same k-order as BK=32 -> bit-identical.
__global__ __launch_bounds__(256) void k_gemm_proj(const short* __restrict__ A,
                                                   const short* __restrict__ B,
                                                   const float* __restrict__ bias,
                                                   float* __restrict__ C) {
    __shared__ __align__(16) short As[32 * 64];    // 4 KB
    __shared__ __align__(16) short Bs[128 * 64];   // 16 KB
    const int tid  = threadIdx.x;
    const int lane = tid & 63, wv = tid >> 6;
    const int wy = wv >> 1, wx = wv & 1;
    const int quad = lane >> 4, l16 = lane & 15;
    const int u = blockIdx.x;
    const int mtile = u & 127;                     // XCD = u%8 = mtile%8
    const int m0 = mtile * 32, n0 = (u >> 7) * 128;
    const int K = 512, N = 512;

    f32x4 acc[4];
    #pragma unroll
    for (int j = 0; j < 4; ++j)
        #pragma unroll
        for (int r = 0; r < 4; ++r) acc[j][r] = 0.f;

    // A: 256 chunks (32 rows x 8), 1/thread; B: 1024 chunks (128 rows x 8), 4/thread
    const short* gA0; short* lA0;
    {
        int c = tid;
        int r = c >> 3, g = (c & 7) ^ (r & 7);
        gA0 = A + (size_t)(m0 + r) * K + g * 8;
        lA0 = &As[(size_t)c * 8];
    }
    const short* gB[4]; short* lB[4];
    #pragma unroll
    for (int i = 0; i < 4; ++i) {
        int c = tid + 256 * i;
        int r = c >> 3, g = (c & 7) ^ (r & 7);
        gB[i] = B + (size_t)(n0 + r) * K + g * 8;
        lB[i] = &Bs[(size_t)c * 8];
    }

    for (int k0 = 0; k0 < K; k0 += 64) {
        __syncthreads();
        GLOAD_LDS16(gA0 + k0, lA0);
        #pragma unroll
        for (int i = 0; i < 4; ++i) GLOAD_LDS16(gB[i] + k0, lB[i]);
        __syncthreads();
        #pragma unroll
        for (int kk = 0; kk < 2; ++kk) {
            const int ra = wy * 16 + l16;
            short8 aF = *(const short8*)&As[(size_t)ra * 64 + (((kk * 4 + quad) ^ (ra & 7)) * 8)];
            #pragma unroll
            for (int nt = 0; nt < 4; ++nt) {
                const int rb = wx * 64 + nt * 16 + l16;
                short8 bF = *(const short8*)&Bs[(size_t)rb * 64 + (((kk * 4 + quad) ^ (rb & 7)) * 8)];
                acc[nt] = __builtin_amdgcn_mfma_f32_16x16x32_bf16(aF, bF, acc[nt], 0, 0, 0);
            }
        }
    }

    float bs[4];
    #pragma unroll
    for (int nt = 0; nt < 4; ++nt) bs[nt] = bias[n0 + wx * 64 + nt * 16 + l16];
    #pragma unroll
    for (int r = 0; r < 4; ++r) {
        int row = m0 + wy * 16 + quad * 4 + r;
        float* Cr = C + (size_t)row * N + n0 + wx * 64 + l16;
        #pragma unroll
        for (int nt = 0; nt < 4; ++nt) Cr[nt * 16] = acc[nt][r] + bs[nt];
    }
}

// ---------- BN finalize + spike + pack (q/k path 4-ch vectorized) ----------
__global__ __launch_bounds__(256) void k_bn_spike(const short* __restrict__ qkvb,
                           const float* __restrict__ psum, const float* __restrict__ psq,
                           const float* __restrict__ gamma, const float* __restrict__ beta,
                           unsigned char* __restrict__ qp, unsigned char* __restrict__ kp,
                           unsigned char* __restrict__ vt) {
    __shared__ float sa[64], sb[64];
    __shared__ __align__(16) unsigned char tile[64 * 80];
    const int tid = threadIdx.x;
    const int slice = blockIdx.x;            // 0..23
    const int c0 = slice * 64;
    const int r0 = blockIdx.y * 256;
    const int b = r0 >> 10, nb = r0 & 1023;

    if (tid < 64) {
        const int c = c0 + tid;
        double s = 0.0, q = 0.0;
        for (int st = 0; st < 32; ++st) { s += (double)psum[st * 1536 + c]; q += (double)psq[st * 1536 + c]; }
        const double mu  = s / 4096.0;
        const double var = q / 4096.0 - mu * mu;
        const float a = (float)((double)gamma[c] / sqrt(var + 1e-5));
        sa[tid] = a;
        sb[tid] = fmaf(-(float)mu, a, beta[c]);
    }
    __syncthreads();

    if (slice < 16) {
        const int h = slice & 7;
        const int ch4 = (tid & 15) * 4, rr = tid >> 4;     // 4 ch/thread, 16 rows/pass
        const float4 A4 = *(const float4*)&sa[ch4];
        const float4 B4 = *(const float4*)&sb[ch4];
        unsigned char* base = (slice < 8 ? qp : kp) + (((size_t)b * 8 + h) * 1024 + nb) * 64;
        for (int i = rr; i < 256; i += 16) {
            const short4v v4 = *(const short4v*)&qkvb[(size_t)(r0 + i) * 1536 + c0 + ch4];
            u8x4 o;
            o.x = (unsigned char)spikef(fmaf(bf2f((unsigned short)v4.x), A4.x, B4.x));
            o.y = (unsigned char)spikef(fmaf(bf2f((unsigned short)v4.y), A4.y, B4.y));
            o.z = (unsigned char)spikef(fmaf(bf2f((unsigned short)v4.z), A4.z, B4.z));
            o.w = (unsigned char)spikef(fmaf(bf2f((unsigned short)v4.w), A4.w, B4.w));
            *(u8x4*)&base[(size_t)i * 64 + ch4] = o;
        }
    } else {
        const int h = slice - 16;
        const int ch = tid & 63, rq = tid >> 6;
        const float A = sa[ch], Bsh = sb[ch];
        const int e = tid >> 2, j0 = (tid & 3) * 16;
        unsigned char* vbase = vt + (((size_t)b * 8 + h) * 64 + e) * 1024 + nb;
        for (int rb = 0; rb < 4; ++rb) {
            __syncthreads();
            for (int i = rq; i < 64; i += 4) {
                float v = bf2f((unsigned short)qkvb[(size_t)(r0 + rb * 64 + i) * 1536 + c0 + ch]);
                tile[ch * 80 + i] = (unsigned char)spikef(fmaf(v, A, Bsh));
            }
            __syncthreads();
            *(u32x4*)&vbase[rb * 64 + j0] = *(const u32x4*)&tile[e * 80 + j0];
        }
    }
}

// ---------- fused i8-MFMA attention, 256-wide j-tiles, glds + XOR-swizzled LDS ----------
__global__ __launch_bounds__(256) void k_attn(const unsigned char* __restrict__ qp,
                                              const unsigned char* __restrict__ kp,
                                              const unsigned char* __restrict__ vt,
                                              short* __restrict__ sout) {
    __shared__ __align__(16) unsigned char SM[54272];
    unsigned char* Qs = SM;                        // 64 x 64B
    unsigned char* Ks = SM + 4096;                 // 256 x 64B
    unsigned char* Vs = SM + 20480;                // 64 x 256B
    unsigned int* Sb = (unsigned int*)(SM + 36864);// 64 x 68 dw
    const int tid  = threadIdx.x;
    const int lane = tid & 63, w = tid >> 6;
    const int quad = lane >> 4, l16 = lane & 15;
    const int u = blockIdx.x;
    const int bhid = u & 31;                       // XCD = u%8 = bhid%8
    const int b = bhid >> 3, h = bhid & 7;
    const int n0 = (u >> 5) * 64;
    const size_t bh = (size_t)b * 8 + h;

    {
        const int r = tid >> 2, p = tid & 3;
        const int g = p ^ (r & 3) ^ ((r >> 2) & 3);
        GLOAD_LDS16(qp + (bh * 1024 + n0 + r) * 64 + g * 16, Qs + (size_t)tid * 16);
    }
    const unsigned char* gK[4]; unsigned char* lK[4];
    const unsigned char* gV[4]; unsigned char* lV[4];
    #pragma unroll
    for (int i = 0; i < 4; ++i) {
        int c = tid + 256 * i;
        int rk = c >> 2, pk2 = c & 3;
        int gk = pk2 ^ (rk & 3) ^ ((rk >> 2) & 3);
        gK[i] = kp + (bh * 1024 + rk) * 64 + gk * 16;
        lK[i] = Ks + (size_t)c * 16;
        int rv = c >> 4, pv = c & 15;
        int gv = pv ^ (rv & 15);
        gV[i] = vt + (bh * 64 + rv) * 1024 + gv * 16;
        lV[i] = Vs + (size_t)c * 16;
    }
    __syncthreads();
    u32x4 qf[4];
    {
        const int pq = quad ^ (l16 & 3) ^ ((l16 >> 2) & 3);
        #pragma unroll
        for (int mt = 0; mt < 4; ++mt)
            qf[mt] = *(const u32x4*)&Qs[(mt * 16 + l16) * 64 + pq * 16];
    }

    int4v of[4];
    #pragma unroll
    for (int mt = 0; mt < 4; ++mt)
        #pragma unroll
        for (int r = 0; r < 4; ++r) of[mt][r] = 0;

    const int pk = quad ^ (l16 & 3) ^ ((l16 >> 2) & 3);

    for (int j0 = 0; j0 < 1024; j0 += 256) {
        __syncthreads();
        #pragma unroll
        for (int i = 0; i < 4; ++i) {
            GLOAD_LDS16(gK[i] + (size_t)j0 * 64, lK[i]);
            GLOAD_LDS16(gV[i] + j0, lV[i]);
        }
        __syncthreads();

        #pragma unroll
        for (int jt = 0; jt < 4; ++jt) {
            u32x4 kf = *(const u32x4*)&Ks[(w * 64 + jt * 16 + l16) * 64 + pk * 16];
            #pragma unroll
            for (int mt = 0; mt < 4; ++mt) {
                int4v z;
                #pragma unroll
                for (int r = 0; r < 4; ++r) z[r] = 0;
                int4v s = mfma_i8(kf, qf[mt], z);
                unsigned int pkk = 0;
                #pragma unroll
                for (int r = 0; r < 4; ++r) {
                    int v = s[r]; v = v < 0 ? 0 : (v > 4 ? 4 : v);
                    pkk |= (unsigned int)v << (8 * r);
                }
                Sb[(mt * 16 + l16) * 68 + w * 16 + jt * 4 + quad] = pkk;
            }
        }
        __syncthreads();

        #pragma unroll
        for (int kk = 0; kk < 4; ++kk) {
            const int pv = (kk * 4 + quad) ^ l16;
            u32x4 bV = *(const u32x4*)&Vs[(w * 16 + l16) * 256 + pv * 16];
            #pragma unroll
            for (int mt = 0; mt < 4; ++mt) {
                u32x4 aS = *(const u32x4*)&Sb[(mt * 16 + l16) * 68 + kk * 16 + quad * 4];
                of[mt] = mfma_i8(aS, bV, of[mt]);
            }
        }
    }

    #pragma unroll
    for (int mt = 0; mt < 4; ++mt)
        #pragma unroll
        for (int r = 0; r < 4; ++r) {
            size_t orow = (size_t)b * 1024 + n0 + mt * 16 + quad * 4 + r;
            sout[orow * 512 + h * 64 + w * 16 + l16] =
                (short)f2bf(spikef((float)of[mt][r] * 0.125f));
        }
}

extern "C" void kernel_launch(void* const* d_in, const int* in_sizes, int n_in,
                              void* d_out, int out_size, void* d_ws, size_t ws_size,
                              hipStream_t stream) {
    const float* x     = (const float*)d_in[0];
    const float* Wqkv  = (const float*)d_in[1];
    const float* gamma = (const float*)d_in[2];
    const float* beta  = (const float*)d_in[3];
    const float* Wproj = (const float*)d_in[4];
    const float* bproj = (const float*)d_in[5];
    float* out = (float*)d_out;

    char* w = (char*)d_ws;
    unsigned char* xs8   = (unsigned char*)(w);             // 2 MB; region reused as sout (4 MB)
    signed char* Wq8     = (signed char*)(w + 8388608);     // 0.75 MB
    float* wscale        = (float*)(w + 9437184);           // 6 KB
    short* Wproj2        = (short*)(w + 11534336);          // 0.5 MB
    short* qkvb          = (short*)(w + 12582912);          // 12 MB (bf16)
    unsigned char* qp    = (unsigned char*)(w + 37748736);  // 2 MB
    unsigned char* kp    = (unsigned char*)(w + 41943040);  // 2 MB
    unsigned char* vt    = (unsigned char*)(w + 46137344);  // 2 MB
    float* psum          = (float*)(w + 50331648);
    float* psq           = psum + 32 * 1536;
    short* sout          = (short*)(w);                     // xs8 dead after qkv GEMM

    k_prep<<<2688, 256, 0, stream>>>(x, Wqkv, Wproj, xs8, Wq8, wscale, Wproj2);
    k_gemm_qkv<<<512, 256, 0, stream>>>(xs8, Wq8, wscale, qkvb, psum, psq);
    k_bn_spike<<<dim3(24, 16), 256, 0, stream>>>(qkvb, psum, psq, gamma, beta, qp, kp, vt);
    k_attn<<<512, 256, 0, stream>>>(qp, kp, vt, sout);
    k_gemm_proj<<<512, 256, 0, stream>>>(sout, Wproj2, bproj, out);
}